// Round 10
// baseline (209.828 us; speedup 1.0000x reference)
//
#include <hip/hip_runtime.h>

typedef __bf16 bf16;
typedef __bf16 bf16x8 __attribute__((ext_vector_type(8)));
typedef __bf16 bf16x4 __attribute__((ext_vector_type(4)));
typedef float  f32x16 __attribute__((ext_vector_type(16)));
typedef unsigned int uint;
typedef unsigned int uintx4 __attribute__((ext_vector_type(4)));

#define QSCALE (0.125f * 1.44269504088896340736f)   // 1/sqrt(64) * log2(e), folded into Q

__device__ __forceinline__ void g2l16(const void* g, void* l) {
  __builtin_amdgcn_global_load_lds(
      (const __attribute__((address_space(1))) void*)g,
      (__attribute__((address_space(3))) void*)l, 16, 0, 0);
}

__device__ __forceinline__ f32x16 mfma16(bf16x8 a, bf16x8 b, f32x16 c) {
  return __builtin_amdgcn_mfma_f32_32x32x16_bf16(a, b, c, 0, 0, 0);
}

// ---------------------------------------------------------------------------
// Session invariants (measured):
//  - attn body is at the 128-VGPR cap: ANY added persistent per-lane state
//    (early V frags, ladd f32x16) spills -> FETCH/WRITE balloon. FETCH/WRITE
//    is the spill tripwire (VGPR_Count stays 64 even when spilling).
//  - LDS slot map must keep lane pairs contiguous in global (g2l16 staging
//    coalescing) even though reads then 2-way bank-alias (free, m136).
// ---------------------------------------------------------------------------

// ---------------------------------------------------------------------------
// f32 -> bf16 casts. seg0: x; seg1..3: Wq/Wk/Wv -> Wqkv; seg4: Wp -> Wpb with
// the differential-combine folded into the weight:
//   Wpb[n,k]      = Wp[n,k]                      (k < 512)
//   Wpb[n,512+j]  = Wp[n,512+j] - lv*Wp[n,j]     (j < 512)
// lv recomputed inline per seg-4 wave (tiny reduction; saves a kernel).
// ---------------------------------------------------------------------------
__global__ void cast5_kernel(const float* __restrict__ x,
                             const float* __restrict__ wq, const float* __restrict__ wk,
                             const float* __restrict__ wv, const float* __restrict__ wp,
                             const float* __restrict__ lq1, const float* __restrict__ lk1,
                             const float* __restrict__ lq2, const float* __restrict__ lk2,
                             bf16* __restrict__ xb, bf16* __restrict__ wqkv,
                             bf16* __restrict__ wpb) {
  int bx = blockIdx.x;
  int seg, idx;
  if (bx < 2048) { seg = 0; idx = bx; }
  else { int t = bx - 2048; seg = 1 + (t >> 9); idx = t & 511; }
  long i = (long)(idx * 256 + threadIdx.x) * 8;
  const float* s; bf16* d;
  if (seg == 0)      { s = x;  d = xb; }
  else if (seg == 1) { s = wq; d = wqkv; }
  else if (seg == 2) { s = wk; d = wqkv + 1048576; }
  else if (seg == 3) { s = wv; d = wqkv + 2097152; }
  else               { s = wp; d = wpb; }
  float4 f0 = *(const float4*)(s + i);
  float4 f1 = *(const float4*)(s + i + 4);
  if (seg == 4 && (i & 1023) >= 512) {
    int t = threadIdx.x & 63;
    float accum = 0.f;
    for (int hh = 0; hh < 8; ++hh) {
      float v1 = lq1[hh*64 + t] * lk1[hh*64 + t];
      float v2 = lq2[hh*64 + t] * lk2[hh*64 + t];
      for (int off = 32; off; off >>= 1) {
        v1 += __shfl_xor(v1, off);
        v2 += __shfl_xor(v2, off);
      }
      accum += expf(fminf(v1, 5.f)) - expf(fminf(v2, 5.f));
    }
    float lv = accum / 8.f + 0.8f;
    float4 g0 = *(const float4*)(s + i - 512);
    float4 g1 = *(const float4*)(s + i - 508);
    f0.x -= lv * g0.x; f0.y -= lv * g0.y; f0.z -= lv * g0.z; f0.w -= lv * g0.w;
    f1.x -= lv * g1.x; f1.y -= lv * g1.y; f1.z -= lv * g1.z; f1.w -= lv * g1.w;
  }
  bf16x8 o;
  o[0] = (bf16)f0.x; o[1] = (bf16)f0.y; o[2] = (bf16)f0.z; o[3] = (bf16)f0.w;
  o[4] = (bf16)f1.x; o[5] = (bf16)f1.y; o[6] = (bf16)f1.z; o[7] = (bf16)f1.w;
  *(bf16x8*)(d + i) = o;
}

// ---------------------------------------------------------------------------
// QKV fused NT GEMM: 128x128 tile, BK=64. grid (32, 24); by = nblk>>3 picks
// Q/K/V. Q scaled by QSCALE. V written transposed AND key-permuted into
// Vt[bh][d][slot]: within each 64-token tile, token tau = 8*Qp + 4*h5 + r
// goes to slot = 16*(Qp>>1) + 8*h5 + 4*(Qp&1) + r.  This permutation makes
// the attention PV B-fragment equal each lane's own 8 consecutive S-regs
// (no cross-lane shuffles) while A-fragment reads stay unchanged.
// v10: Vt store goes through a padded LDS tile so global stores are
// row-contiguous (256B/instr coalesced) instead of 8B x 32-line scatter.
// ---------------------------------------------------------------------------
__global__ __launch_bounds__(256, 2) void gemm_qkv_kernel(
    const bf16* __restrict__ A, const bf16* __restrict__ B,
    const float* __restrict__ bias0, const float* __restrict__ bias1,
    const float* __restrict__ bias2,
    bf16* __restrict__ O0, bf16* __restrict__ O1, bf16* __restrict__ O2) {
  __shared__ __align__(16) char smem[34 * 1024];   // K-loop uses 32KB; V-epi 33KB
  const int tid = threadIdx.x;
  const int w = tid >> 6, L = tid & 63;
  const int l31 = L & 31, h5 = L >> 5;
  const int m0 = blockIdx.x * 128;
  const int n0g = blockIdx.y * 128;
  const int by = n0g >> 10;
  const bf16* Bp = B + (long)by * 1048576;
  const float* biasp = (by == 0) ? bias0 : ((by == 1) ? bias1 : bias2);
  const int nloc = n0g & 1023;

  f32x16 acc[2][2];
  for (int i = 0; i < 2; ++i) for (int j = 0; j < 2; ++j)
    for (int r = 0; r < 16; ++r) acc[i][j][r] = 0.f;

  const int srow = L >> 1, spar = L & 1;
  const int wm = w >> 1, wn = w & 1;
  const int fs = (l31 * 2 + h5) * 16;

  for (int k0 = 0; k0 < 1024; k0 += 64) {
    for (int i = 0; i < 8; ++i) {
      int r = w * 8 + i;
      int rr = r & 15;
      int rowblk = rr >> 2, kst = rr & 3;
      int row = rowblk * 32 + srow;
      int kk = k0 + (kst * 2 + spar) * 8;
      const bf16* gsrc = (r < 16) ? (A + (long)(m0 + row) * 1024 + kk)
                                  : (Bp + (long)(nloc + row) * 1024 + kk);
      g2l16(gsrc, smem + r * 1024);
    }
    __syncthreads();
    for (int kst = 0; kst < 4; ++kst) {
      bf16x8 a0 = *(const bf16x8*)(smem + (((wm * 2 + 0) * 4 + kst) * 1024) + fs);
      bf16x8 a1 = *(const bf16x8*)(smem + (((wm * 2 + 1) * 4 + kst) * 1024) + fs);
      bf16x8 b0 = *(const bf16x8*)(smem + 16384 + (((wn * 2 + 0) * 4 + kst) * 1024) + fs);
      bf16x8 b1 = *(const bf16x8*)(smem + 16384 + (((wn * 2 + 1) * 4 + kst) * 1024) + fs);
      acc[0][0] = mfma16(a0, b0, acc[0][0]);
      acc[0][1] = mfma16(a0, b1, acc[0][1]);
      acc[1][0] = mfma16(a1, b0, acc[1][0]);
      acc[1][1] = mfma16(a1, b1, acc[1][1]);
    }
    __syncthreads();
  }

  if (by == 2) {
    // ---- V epilogue via LDS bounce ----
    bf16* vt = (bf16*)smem;
    int b = m0 >> 11;
    int nbase = (m0 & 2047);
    for (int mi = 0; mi < 2; ++mi) for (int ni = 0; ni < 2; ++ni) {
      int lcol = wn * 64 + ni * 32 + l31;
      float bias_v = biasp[nloc + lcol];
      for (int g = 0; g < 4; ++g) {
        bf16x4 pk;
        for (int r = 0; r < 4; ++r) pk[r] = (bf16)(acc[mi][ni][g * 4 + r] + bias_v);
        int Qp = mi * 4 + g;
        int lslot = wm * 64 + (Qp >> 1) * 16 + h5 * 8 + (Qp & 1) * 4;
        *(bf16x4*)(vt + lcol * 132 + lslot) = pk;
      }
    }
    __syncthreads();
    for (int rr = 0; rr < 32; ++rr) {
      int lcol = w * 32 + rr;
      int col = nloc + lcol;
      int hh = col >> 6, d = col & 63;
      uint val = *(const uint*)(vt + lcol * 132 + L * 2);
      *(uint*)(O2 + ((long)(b * 16 + hh) * 64 + d) * 2048 + nbase + L * 2) = val;
    }
  } else {
    bf16* dst = (by == 0) ? O0 : O1;
    float scale = (by == 0) ? QSCALE : 1.0f;
    for (int mi = 0; mi < 2; ++mi) for (int ni = 0; ni < 2; ++ni) {
      int col = nloc + wn * 64 + ni * 32 + l31;
      float bias_v = biasp[col];
      int row_base = m0 + wm * 64 + mi * 32 + 4 * h5;
      for (int reg = 0; reg < 16; ++reg) {
        int rowoff = (reg & 3) + 8 * (reg >> 2);
        float v = (acc[mi][ni][reg] + bias_v) * scale;
        dst[(long)(row_base + rowoff) * 1024 + col] = (bf16)v;
      }
    }
  }
}

// ---------------------------------------------------------------------------
// Projection GEMM: 128x128 tile, clone of the proven gemm_qkv loop, f32 out
// + bias. grid (32,8) = 256 blocks.
// ---------------------------------------------------------------------------
__global__ __launch_bounds__(256, 2) void gemm_proj_kernel(
    const bf16* __restrict__ A, const bf16* __restrict__ B,
    const float* __restrict__ bias, float* __restrict__ Of) {
  __shared__ __align__(16) char smem[32 * 1024];
  const int tid = threadIdx.x;
  const int w = tid >> 6, L = tid & 63;
  const int l31 = L & 31, h5 = L >> 5;
  const int m0 = blockIdx.x * 128;
  const int n0 = blockIdx.y * 128;

  f32x16 acc[2][2];
  for (int i = 0; i < 2; ++i) for (int j = 0; j < 2; ++j)
    for (int r = 0; r < 16; ++r) acc[i][j][r] = 0.f;

  const int srow = L >> 1, spar = L & 1;
  const int wm = w >> 1, wn = w & 1;
  const int fs = (l31 * 2 + h5) * 16;

  for (int k0 = 0; k0 < 1024; k0 += 64) {
    for (int i = 0; i < 8; ++i) {
      int r = w * 8 + i;
      int rr = r & 15;
      int rowblk = rr >> 2, kst = rr & 3;
      int row = rowblk * 32 + srow;
      int kk = k0 + (kst * 2 + spar) * 8;
      const bf16* gsrc = (r < 16) ? (A + (long)(m0 + row) * 1024 + kk)
                                  : (B + (long)(n0 + row) * 1024 + kk);
      g2l16(gsrc, smem + r * 1024);
    }
    __syncthreads();
    for (int kst = 0; kst < 4; ++kst) {
      bf16x8 a0 = *(const bf16x8*)(smem + (((wm * 2 + 0) * 4 + kst) * 1024) + fs);
      bf16x8 a1 = *(const bf16x8*)(smem + (((wm * 2 + 1) * 4 + kst) * 1024) + fs);
      bf16x8 b0 = *(const bf16x8*)(smem + 16384 + (((wn * 2 + 0) * 4 + kst) * 1024) + fs);
      bf16x8 b1 = *(const bf16x8*)(smem + 16384 + (((wn * 2 + 1) * 4 + kst) * 1024) + fs);
      acc[0][0] = mfma16(a0, b0, acc[0][0]);
      acc[0][1] = mfma16(a0, b1, acc[0][1]);
      acc[1][0] = mfma16(a1, b0, acc[1][0]);
      acc[1][1] = mfma16(a1, b1, acc[1][1]);
    }
    __syncthreads();
  }

  for (int mi = 0; mi < 2; ++mi) for (int ni = 0; ni < 2; ++ni) {
    int col = n0 + wn * 64 + ni * 32 + l31;
    float bias_v = bias[col];
    int row_base = m0 + wm * 64 + mi * 32 + 4 * h5;
    for (int reg = 0; reg < 16; ++reg) {
      int rowoff = (reg & 3) + 8 * (reg >> 2);
      Of[(long)(row_base + rowoff) * 1024 + col] = acc[mi][ni][reg] + bias_v;
    }
  }
}

// ---------------------------------------------------------------------------
// Flash attention v11: occupancy restructure. grid (32 bh, 32 qt), 256 thr
// = 4 waves (2 halves x 2 pairs), 64 q-rows per block, 4 blocks/CU
// (LDS 32KB, launch_bounds(256,4) keeps the proven 128-VGPR cap).
// Single K+V buffer per half (16KB), latency hidden by staged roles:
//   pair-0 waves stage K, pair-1 waves stage V.
//   iter t: [K-stager vmcnt(0)] bar1 -> QK^T -> bar2 -> stageK(t+1)
//           exp -> [V-stager vmcnt(0)] bar3 -> PV -> bar4 -> stageV(t+1)
// K(t+1) lands under exp+PV+next-QK^T; V(t+1) lands under next QK^T+exp.
// 4 independent barrier domains per CU (vs 2) overlap each other's stalls.
// Per-wave compute body is byte-identical to v5 (proven, at VGPR cap).
// ---------------------------------------------------------------------------
__global__ __launch_bounds__(256, 4) void attn_kernel(
    const bf16* __restrict__ Qb, const bf16* __restrict__ Kb,
    const bf16* __restrict__ Vt, bf16* __restrict__ Ob) {
  // staging: [half][K 8KB | V 8KB] = 32KB. epilogue (reuses bytes after the
  // loop): O-exchange 2 pairs x 8448B = 16896, l at 16896..17152,
  // transpose 2 x 4352B.
  __shared__ __align__(16) char smem[32768];
  const int tid = threadIdx.x, w = tid >> 6, L = tid & 63;
  const int half = w >> 1, pair = w & 1;
  const int bh = blockIdx.x, qt = blockIdx.y;
  const int b = bh >> 4, h = bh & 15;
  const int q0 = qt * 64 + pair * 32;
  const int l31 = L & 31, h5 = L >> 5;
  const int srow = L >> 1, spar = L & 1;
  const int fs = (l31 * 2 + h5) * 16;

  // Q fragments (B-operand of S^T mfma), resident for the whole K loop
  bf16x8 qf[4];
  for (int kst = 0; kst < 4; ++kst)
    qf[kst] = *(const bf16x8*)(Qb + (long)(b * 2048 + q0 + l31) * 1024 + h * 64
                               + kst * 16 + h5 * 8);

  f32x16 o[2];  // [di] : O^T rows d, cols q (unnormalized partial)
  for (int i = 0; i < 2; ++i)
    for (int r = 0; r < 16; ++r) o[i][r] = 0.f;
  float ls[4] = {0.f, 0.f, 0.f, 0.f};  // 4-way partial l

  const bf16* Kbh = Kb + (long)b * 2048 * 1024 + h * 64 + (long)half * 1024 * 1024;
  const bf16* Vth = Vt + (long)bh * 64 * 2048 + half * 1024;

  char* kbase = smem + half * 16384;   // K: +0..8KB, V: +8..16KB

  // pair-0 waves stage all 8 K regions; pair-1 waves all 8 V regions.
  auto stageK = [&](int t) {
    int n0 = t * 64;
    for (int r = 0; r < 8; ++r) {
      const bf16* g = Kbh + (long)(n0 + (r >> 2) * 32 + srow) * 1024
                      + ((r & 3) * 2 + spar) * 8;
      g2l16(g, kbase + r * 1024);
    }
  };
  auto stageV = [&](int t) {
    int n0 = t * 64;
    for (int rr = 0; rr < 8; ++rr) {
      const bf16* g = Vth + (long)((rr >> 2) * 32 + srow) * 2048 + n0
                      + ((rr & 3) * 2 + spar) * 8;
      g2l16(g, kbase + 8192 + rr * 1024);
    }
  };

  if (pair == 0) stageK(0); else stageV(0);

  for (int t = 0; t < 16; ++t) {
    // ---- K(t) visibility: producer waits own loads, then barrier ----
    if (pair == 0) asm volatile("s_waitcnt vmcnt(0)" ::: "memory");
    __builtin_amdgcn_s_barrier();
    __builtin_amdgcn_sched_barrier(0);

    // S^T[key][q]; zero-C folded into kst=0
    f32x16 s[2];
    {
      bf16x8 k0f = *(const bf16x8*)(kbase + fs);
      bf16x8 k1f = *(const bf16x8*)(kbase + 4 * 1024 + fs);
      f32x16 z = {};
      __builtin_amdgcn_s_setprio(1);
      s[0] = mfma16(k0f, qf[0], z);
      s[1] = mfma16(k1f, qf[0], z);
      __builtin_amdgcn_s_setprio(0);
    }
    for (int kst = 1; kst < 4; ++kst) {
      bf16x8 k0f = *(const bf16x8*)(kbase + (kst * 1024) + fs);
      bf16x8 k1f = *(const bf16x8*)(kbase + ((4 + kst) * 1024) + fs);
      __builtin_amdgcn_s_setprio(1);
      s[0] = mfma16(k0f, qf[kst], s[0]);
      s[1] = mfma16(k1f, qf[kst], s[1]);
      __builtin_amdgcn_s_setprio(0);
    }

    // ---- all waves done reading K(t) -> restage K(t+1) now; its latency
    // hides under exp + PV + next iter's top ----
    __builtin_amdgcn_s_barrier();
    if (pair == 0 && t + 1 < 16) stageK(t + 1);

    // p = exp2(s); accumulate l into 4 partials
    for (int nki = 0; nki < 2; ++nki)
      for (int r = 0; r < 16; ++r) {
        float p = __builtin_amdgcn_exp2f(s[nki][r]);
        s[nki][r] = p;
        ls[r & 3] += p;
      }

    // ---- V(t) visibility (issued end of iter t-1; hidden under QK^T+exp) ----
    if (pair == 1) asm volatile("s_waitcnt vmcnt(0)" ::: "memory");
    __builtin_amdgcn_s_barrier();
    __builtin_amdgcn_sched_barrier(0);

    // O^T += Vt_tile · P^T.  Vt global layout is key-permuted so that the
    // B-fragment for kst is exactly s[kst>>1][8*(kst&1) + 0..7] in order.
    for (int kst = 0; kst < 4; ++kst) {
      bf16x8 v0 = *(const bf16x8*)(kbase + 8192 + (kst * 1024) + fs);
      bf16x8 v1 = *(const bf16x8*)(kbase + 8192 + ((4 + kst) * 1024) + fs);
      int nki = kst >> 1;
      int rbase = (kst & 1) * 8;
      bf16x8 pf;   // direct casts -> v_cvt_pk_bf16_f32 pairs (m240)
#pragma unroll
      for (int j = 0; j < 8; ++j) pf[j] = (bf16)s[nki][rbase + j];
      __builtin_amdgcn_s_setprio(1);
      o[0] = mfma16(v0, pf, o[0]);
      o[1] = mfma16(v1, pf, o[1]);
      __builtin_amdgcn_s_setprio(0);
    }

    // ---- all waves done reading V(t) -> restage V(t+1) ----
    __builtin_amdgcn_s_barrier();
    if (pair == 1 && t + 1 < 16) stageV(t + 1);
  }

  // ---- combine halves through LDS (exact f32 add), then normalize ----
  float lsum = (ls[0] + ls[1]) + (ls[2] + ls[3]);
  float lcol = lsum + __shfl_xor(lsum, 32);  // per-col l of this half
  if (half) {
    float* dstO = (float*)smem + pair * 2112;   // stride 33 dwords: bank-free
    for (int di = 0; di < 2; ++di)
      for (int r = 0; r < 16; ++r) dstO[L * 33 + di * 16 + r] = o[di][r];
    if (h5 == 0) ((float*)(smem + 16896))[pair * 32 + l31] = lcol;
  }
  __syncthreads();
  float linv = 0.f;
  if (!half) {
    float* srcO = (float*)smem + pair * 2112;
    for (int di = 0; di < 2; ++di)
      for (int r = 0; r < 16; ++r) o[di][r] += srcO[L * 33 + di * 16 + r];
    float lother = ((float*)(smem + 16896))[pair * 32 + l31];
    linv = 1.f / (lcol + lother);
  }
  __syncthreads();
  if (!half) {
    // O^T/l -> per-wave LDS tile [32 q][68 d-stride] -> coalesced store
    char* ot = smem + pair * 4352;
    for (int di = 0; di < 2; ++di)
      for (int g = 0; g < 4; ++g) {
        bf16x4 pk;
        for (int r = 0; r < 4; ++r)
          pk[r] = (bf16)(o[di][g * 4 + r] * linv);
        int d0 = di * 32 + g * 8 + h5 * 4;
        *(bf16x4*)(ot + (l31 * 68 + d0) * 2) = pk;
      }
    for (int i = 0; i < 4; ++i) {
      int qloc = (L >> 3) + i * 8;
      int cc = L & 7;
      bf16x8 vv = *(const bf16x8*)(ot + (qloc * 68 + cc * 8) * 2);
      *(bf16x8*)(Ob + (long)(b * 2048 + q0 + qloc) * 1024 + h * 64 + cc * 8) = vv;
    }
  }
}

// ---------------------------------------------------------------------------
extern "C" void kernel_launch(void* const* d_in, const int* in_sizes, int n_in,
                              void* d_out, int out_size, void* d_ws, size_t ws_size,
                              hipStream_t stream) {
  const float* x   = (const float*)d_in[0];
  const float* Wq  = (const float*)d_in[1];
  const float* bq  = (const float*)d_in[2];
  const float* Wk  = (const float*)d_in[3];
  const float* bk  = (const float*)d_in[4];
  const float* Wv  = (const float*)d_in[5];
  const float* bv  = (const float*)d_in[6];
  const float* Wp  = (const float*)d_in[7];
  const float* bp  = (const float*)d_in[8];
  const float* lq1 = (const float*)d_in[9];
  const float* lk1 = (const float*)d_in[10];
  const float* lq2 = (const float*)d_in[11];
  const float* lk2 = (const float*)d_in[12];
  float* out = (float*)d_out;

  // ws layout: pad | xb(8MB) | Wqkv(6MB) | Wpb(2MB) | Vt(8MB) | Ob(8MB)
  char* ws = (char*)d_ws;
  bf16* xb   = (bf16*)(ws + 1024);
  bf16* Wqkv = xb + (long)4096 * 1024;
  bf16* Wpb  = Wqkv + (long)3 * 1024 * 1024;
  bf16* Vt   = Wpb + (long)1024 * 1024;       // [32 bh][64 d][2048 slot]
  bf16* Ob   = Vt + (long)4096 * 1024;
  // Q/K bf16 tensors live in d_out (16MB); dead before final GEMM writes it
  bf16* Qb = (bf16*)d_out;
  bf16* Kb = Qb + (long)4096 * 1024;

  cast5_kernel<<<dim3(4096), 256, 0, stream>>>(
      x, Wq, Wk, Wv, Wp, lq1, lk1, lq2, lk2, xb, Wqkv, Wpb);
  gemm_qkv_kernel<<<dim3(32, 24), 256, 0, stream>>>(
      xb, Wqkv, bq, bk, bv, Qb, Kb, Vt);
  attn_kernel<<<dim3(32, 32), 256, 0, stream>>>(Qb, Kb, Vt, Ob);
  gemm_proj_kernel<<<dim3(32, 8), 256, 0, stream>>>(Ob, Wpb, bp, out);
}

// Round 11
// 205.988 us; speedup vs baseline: 1.0186x; 1.0186x over previous
//
#include <hip/hip_runtime.h>

typedef __bf16 bf16;
typedef __bf16 bf16x8 __attribute__((ext_vector_type(8)));
typedef __bf16 bf16x4 __attribute__((ext_vector_type(4)));
typedef float  f32x16 __attribute__((ext_vector_type(16)));
typedef unsigned int uint;
typedef unsigned int uintx4 __attribute__((ext_vector_type(4)));

#define QSCALE (0.125f * 1.44269504088896340736f)   // 1/sqrt(64) * log2(e), folded into Q

__device__ __forceinline__ void g2l16(const void* g, void* l) {
  __builtin_amdgcn_global_load_lds(
      (const __attribute__((address_space(1))) void*)g,
      (__attribute__((address_space(3))) void*)l, 16, 0, 0);
}

__device__ __forceinline__ f32x16 mfma16(bf16x8 a, bf16x8 b, f32x16 c) {
  return __builtin_amdgcn_mfma_f32_32x32x16_bf16(a, b, c, 0, 0, 0);
}

// ---------------------------------------------------------------------------
// Session invariants (measured):
//  - attn body is at the 128-VGPR cap: ANY added persistent per-lane state
//    spills -> FETCH/WRITE balloon (the spill tripwire; VGPR_Count lies).
//  - LDS slot map must keep lane pairs contiguous in global (g2l16 staging
//    coalescing); the 2-way read bank-alias is free (m136).
//  - 16 waves/CU is fixed: grid 512x8w = 1024x4w (v11 proved repartition
//    is not occupancy).
// ---------------------------------------------------------------------------

// ---------------------------------------------------------------------------
// f32 -> bf16 casts. seg0: x; seg1..3: Wq/Wk/Wv -> Wqkv; seg4: Wp -> Wpb with
// the differential-combine folded into the weight.
// ---------------------------------------------------------------------------
__global__ void cast5_kernel(const float* __restrict__ x,
                             const float* __restrict__ wq, const float* __restrict__ wk,
                             const float* __restrict__ wv, const float* __restrict__ wp,
                             const float* __restrict__ lq1, const float* __restrict__ lk1,
                             const float* __restrict__ lq2, const float* __restrict__ lk2,
                             bf16* __restrict__ xb, bf16* __restrict__ wqkv,
                             bf16* __restrict__ wpb) {
  int bx = blockIdx.x;
  int seg, idx;
  if (bx < 2048) { seg = 0; idx = bx; }
  else { int t = bx - 2048; seg = 1 + (t >> 9); idx = t & 511; }
  long i = (long)(idx * 256 + threadIdx.x) * 8;
  const float* s; bf16* d;
  if (seg == 0)      { s = x;  d = xb; }
  else if (seg == 1) { s = wq; d = wqkv; }
  else if (seg == 2) { s = wk; d = wqkv + 1048576; }
  else if (seg == 3) { s = wv; d = wqkv + 2097152; }
  else               { s = wp; d = wpb; }
  float4 f0 = *(const float4*)(s + i);
  float4 f1 = *(const float4*)(s + i + 4);
  if (seg == 4 && (i & 1023) >= 512) {
    int t = threadIdx.x & 63;
    float accum = 0.f;
    for (int hh = 0; hh < 8; ++hh) {
      float v1 = lq1[hh*64 + t] * lk1[hh*64 + t];
      float v2 = lq2[hh*64 + t] * lk2[hh*64 + t];
      for (int off = 32; off; off >>= 1) {
        v1 += __shfl_xor(v1, off);
        v2 += __shfl_xor(v2, off);
      }
      accum += expf(fminf(v1, 5.f)) - expf(fminf(v2, 5.f));
    }
    float lv = accum / 8.f + 0.8f;
    float4 g0 = *(const float4*)(s + i - 512);
    float4 g1 = *(const float4*)(s + i - 508);
    f0.x -= lv * g0.x; f0.y -= lv * g0.y; f0.z -= lv * g0.z; f0.w -= lv * g0.w;
    f1.x -= lv * g1.x; f1.y -= lv * g1.y; f1.z -= lv * g1.z; f1.w -= lv * g1.w;
  }
  bf16x8 o;
  o[0] = (bf16)f0.x; o[1] = (bf16)f0.y; o[2] = (bf16)f0.z; o[3] = (bf16)f0.w;
  o[4] = (bf16)f1.x; o[5] = (bf16)f1.y; o[6] = (bf16)f1.z; o[7] = (bf16)f1.w;
  *(bf16x8*)(d + i) = o;
}

// ---------------------------------------------------------------------------
// QKV fused NT GEMM: 128x128 tile, BK=64. grid (32, 24); by = nblk>>3 picks
// Q/K/V. Q scaled by QSCALE. V written transposed AND key-permuted into
// Vt[bh][d][slot] (slot = 16*(Qp>>1) + 8*h5 + 4*(Qp&1) + r for token
// tau = 8*Qp + 4*h5 + r) so the attention PV B-fragment is each lane's own
// 8 consecutive S-regs. V epilogue goes through a padded LDS tile so global
// stores are row-contiguous (256B/instr).
// ---------------------------------------------------------------------------
__global__ __launch_bounds__(256, 2) void gemm_qkv_kernel(
    const bf16* __restrict__ A, const bf16* __restrict__ B,
    const float* __restrict__ bias0, const float* __restrict__ bias1,
    const float* __restrict__ bias2,
    bf16* __restrict__ O0, bf16* __restrict__ O1, bf16* __restrict__ O2) {
  __shared__ __align__(16) char smem[34 * 1024];   // K-loop uses 32KB; V-epi 33KB
  const int tid = threadIdx.x;
  const int w = tid >> 6, L = tid & 63;
  const int l31 = L & 31, h5 = L >> 5;
  const int m0 = blockIdx.x * 128;
  const int n0g = blockIdx.y * 128;
  const int by = n0g >> 10;
  const bf16* Bp = B + (long)by * 1048576;
  const float* biasp = (by == 0) ? bias0 : ((by == 1) ? bias1 : bias2);
  const int nloc = n0g & 1023;

  f32x16 acc[2][2];
  for (int i = 0; i < 2; ++i) for (int j = 0; j < 2; ++j)
    for (int r = 0; r < 16; ++r) acc[i][j][r] = 0.f;

  const int srow = L >> 1, spar = L & 1;
  const int wm = w >> 1, wn = w & 1;
  const int fs = (l31 * 2 + h5) * 16;

  for (int k0 = 0; k0 < 1024; k0 += 64) {
    for (int i = 0; i < 8; ++i) {
      int r = w * 8 + i;
      int rr = r & 15;
      int rowblk = rr >> 2, kst = rr & 3;
      int row = rowblk * 32 + srow;
      int kk = k0 + (kst * 2 + spar) * 8;
      const bf16* gsrc = (r < 16) ? (A + (long)(m0 + row) * 1024 + kk)
                                  : (Bp + (long)(nloc + row) * 1024 + kk);
      g2l16(gsrc, smem + r * 1024);
    }
    __syncthreads();
    for (int kst = 0; kst < 4; ++kst) {
      bf16x8 a0 = *(const bf16x8*)(smem + (((wm * 2 + 0) * 4 + kst) * 1024) + fs);
      bf16x8 a1 = *(const bf16x8*)(smem + (((wm * 2 + 1) * 4 + kst) * 1024) + fs);
      bf16x8 b0 = *(const bf16x8*)(smem + 16384 + (((wn * 2 + 0) * 4 + kst) * 1024) + fs);
      bf16x8 b1 = *(const bf16x8*)(smem + 16384 + (((wn * 2 + 1) * 4 + kst) * 1024) + fs);
      acc[0][0] = mfma16(a0, b0, acc[0][0]);
      acc[0][1] = mfma16(a0, b1, acc[0][1]);
      acc[1][0] = mfma16(a1, b0, acc[1][0]);
      acc[1][1] = mfma16(a1, b1, acc[1][1]);
    }
    __syncthreads();
  }

  if (by == 2) {
    // ---- V epilogue via LDS bounce ----
    bf16* vt = (bf16*)smem;
    int b = m0 >> 11;
    int nbase = (m0 & 2047);
    for (int mi = 0; mi < 2; ++mi) for (int ni = 0; ni < 2; ++ni) {
      int lcol = wn * 64 + ni * 32 + l31;
      float bias_v = biasp[nloc + lcol];
      for (int g = 0; g < 4; ++g) {
        bf16x4 pk;
        for (int r = 0; r < 4; ++r) pk[r] = (bf16)(acc[mi][ni][g * 4 + r] + bias_v);
        int Qp = mi * 4 + g;
        int lslot = wm * 64 + (Qp >> 1) * 16 + h5 * 8 + (Qp & 1) * 4;
        *(bf16x4*)(vt + lcol * 132 + lslot) = pk;
      }
    }
    __syncthreads();
    for (int rr = 0; rr < 32; ++rr) {
      int lcol = w * 32 + rr;
      int col = nloc + lcol;
      int hh = col >> 6, d = col & 63;
      uint val = *(const uint*)(vt + lcol * 132 + L * 2);
      *(uint*)(O2 + ((long)(b * 16 + hh) * 64 + d) * 2048 + nbase + L * 2) = val;
    }
  } else {
    bf16* dst = (by == 0) ? O0 : O1;
    float scale = (by == 0) ? QSCALE : 1.0f;
    for (int mi = 0; mi < 2; ++mi) for (int ni = 0; ni < 2; ++ni) {
      int col = nloc + wn * 64 + ni * 32 + l31;
      float bias_v = biasp[col];
      int row_base = m0 + wm * 64 + mi * 32 + 4 * h5;
      for (int reg = 0; reg < 16; ++reg) {
        int rowoff = (reg & 3) + 8 * (reg >> 2);
        float v = (acc[mi][ni][reg] + bias_v) * scale;
        dst[(long)(row_base + rowoff) * 1024 + col] = (bf16)v;
      }
    }
  }
}

// ---------------------------------------------------------------------------
// Projection GEMM: 128x128 tile, clone of the proven gemm_qkv loop, f32 out
// + bias. grid (32,8) = 256 blocks.
// ---------------------------------------------------------------------------
__global__ __launch_bounds__(256, 2) void gemm_proj_kernel(
    const bf16* __restrict__ A, const bf16* __restrict__ B,
    const float* __restrict__ bias, float* __restrict__ Of) {
  __shared__ __align__(16) char smem[32 * 1024];
  const int tid = threadIdx.x;
  const int w = tid >> 6, L = tid & 63;
  const int l31 = L & 31, h5 = L >> 5;
  const int m0 = blockIdx.x * 128;
  const int n0 = blockIdx.y * 128;

  f32x16 acc[2][2];
  for (int i = 0; i < 2; ++i) for (int j = 0; j < 2; ++j)
    for (int r = 0; r < 16; ++r) acc[i][j][r] = 0.f;

  const int srow = L >> 1, spar = L & 1;
  const int wm = w >> 1, wn = w & 1;
  const int fs = (l31 * 2 + h5) * 16;

  for (int k0 = 0; k0 < 1024; k0 += 64) {
    for (int i = 0; i < 8; ++i) {
      int r = w * 8 + i;
      int rr = r & 15;
      int rowblk = rr >> 2, kst = rr & 3;
      int row = rowblk * 32 + srow;
      int kk = k0 + (kst * 2 + spar) * 8;
      const bf16* gsrc = (r < 16) ? (A + (long)(m0 + row) * 1024 + kk)
                                  : (B + (long)(n0 + row) * 1024 + kk);
      g2l16(gsrc, smem + r * 1024);
    }
    __syncthreads();
    for (int kst = 0; kst < 4; ++kst) {
      bf16x8 a0 = *(const bf16x8*)(smem + (((wm * 2 + 0) * 4 + kst) * 1024) + fs);
      bf16x8 a1 = *(const bf16x8*)(smem + (((wm * 2 + 1) * 4 + kst) * 1024) + fs);
      bf16x8 b0 = *(const bf16x8*)(smem + 16384 + (((wn * 2 + 0) * 4 + kst) * 1024) + fs);
      bf16x8 b1 = *(const bf16x8*)(smem + 16384 + (((wn * 2 + 1) * 4 + kst) * 1024) + fs);
      acc[0][0] = mfma16(a0, b0, acc[0][0]);
      acc[0][1] = mfma16(a0, b1, acc[0][1]);
      acc[1][0] = mfma16(a1, b0, acc[1][0]);
      acc[1][1] = mfma16(a1, b1, acc[1][1]);
    }
    __syncthreads();
  }

  for (int mi = 0; mi < 2; ++mi) for (int ni = 0; ni < 2; ++ni) {
    int col = n0 + wn * 64 + ni * 32 + l31;
    float bias_v = bias[col];
    int row_base = m0 + wm * 64 + mi * 32 + 4 * h5;
    for (int reg = 0; reg < 16; ++reg) {
      int rowoff = (reg & 3) + 8 * (reg >> 2);
      Of[(long)(row_base + rowoff) * 1024 + col] = acc[mi][ni][reg] + bias_v;
    }
  }
}

// ---------------------------------------------------------------------------
// Flash attention, intra-block K-split (64-key tiles, 16 iters). grid
// (32 bh, 16 qt), 512 thr = 8 waves; anchor v5 staging (double-buffered,
// counted vmcnt(4)).
//
// v12 = v5 + single-wave ILP interleave (zero new state, same instruction
// multiset): the exp/cvt VALU work is moved INTO the shadows of independent
// MFMA clusters in source order:
//   QK(s0) -> { QK(s1) || exp(s0) } -> { PV0 || exp(s1)lo }
//          -> { PV1 || exp(s1)hi } -> PV2, PV3
// setprio only on pure-MFMA clusters. s0/s1 lifetimes unchanged -> no spill.
// ---------------------------------------------------------------------------
__global__ __launch_bounds__(512, 4) void attn_kernel(
    const bf16* __restrict__ Qb, const bf16* __restrict__ Kb,
    const bf16* __restrict__ Vt, bf16* __restrict__ Ob) {
  // staging: buf{0,1} x [half][K 8KB | V 8KB] = 64KB.  epilogue reuses bytes.
  __shared__ __align__(16) char smem[65536];
  const int tid = threadIdx.x, w = tid >> 6, L = tid & 63;
  const int half = w >> 2, pair = w & 3;
  const int bh = blockIdx.x, qt = blockIdx.y;
  const int b = bh >> 4, h = bh & 15;
  const int q0 = qt * 128 + pair * 32;
  const int l31 = L & 31, h5 = L >> 5;
  const int srow = L >> 1, spar = L & 1;
  const int fs = (l31 * 2 + h5) * 16;

  // Q fragments (B-operand of S^T mfma), resident for the whole K loop
  bf16x8 qf[4];
  for (int kst = 0; kst < 4; ++kst)
    qf[kst] = *(const bf16x8*)(Qb + (long)(b * 2048 + q0 + l31) * 1024 + h * 64
                               + kst * 16 + h5 * 8);

  f32x16 o[2];  // [di] : O^T rows d, cols q (unnormalized partial)
  for (int i = 0; i < 2; ++i)
    for (int r = 0; r < 16; ++r) o[i][r] = 0.f;
  float ls[4] = {0.f, 0.f, 0.f, 0.f};  // 4-way partial l

  const bf16* Kbh = Kb + (long)b * 2048 * 1024 + h * 64 + (long)half * 1024 * 1024;
  const bf16* Vth = Vt + (long)bh * 64 * 2048 + half * 1024;

  char* kb0 = smem + half * 16384;            // buffer 0 (this half)
  char* kb1 = smem + 32768 + half * 16384;    // buffer 1 (this half)

  // stage tile t into buffer kb: 4 global_load_lds per wave, 16 regions/half
  auto stage = [&](int t, char* kb) {
    int n0 = t * 64;
    for (int i = 0; i < 4; ++i) {
      int r = pair * 4 + i;
      if (r < 8) {
        int nkb = r >> 2, kst = r & 3;
        const bf16* g = Kbh + (long)(n0 + nkb * 32 + srow) * 1024 + (kst * 2 + spar) * 8;
        g2l16(g, kb + r * 1024);
      } else {
        int rr = r - 8, db = rr >> 2, kst = rr & 3;
        const bf16* g = Vth + (long)(db * 32 + srow) * 2048 + n0 + (kst * 2 + spar) * 8;
        g2l16(g, kb + 8192 + rr * 1024);
      }
    }
  };

  stage(0, kb0);   // 4 loads in flight
  stage(1, kb1);   // 8 loads in flight

  for (int t = 0; t < 16; ++t) {
    char* kb = (t & 1) ? kb1 : kb0;
    // wait for THIS tile's stage (the 4 oldest); leave next tile's in flight
    if (t < 15) asm volatile("s_waitcnt vmcnt(4)" ::: "memory");
    else        asm volatile("s_waitcnt vmcnt(0)" ::: "memory");
    __builtin_amdgcn_s_barrier();

    // ---- phase 1: QK for s0 (K regions 0-3), pure MFMA ----
    f32x16 s0, s1;
    {
      bf16x8 ka0 = *(const bf16x8*)(kb + 0 * 1024 + fs);
      bf16x8 ka1 = *(const bf16x8*)(kb + 1 * 1024 + fs);
      bf16x8 ka2 = *(const bf16x8*)(kb + 2 * 1024 + fs);
      bf16x8 ka3 = *(const bf16x8*)(kb + 3 * 1024 + fs);
      f32x16 z = {};
      __builtin_amdgcn_s_setprio(1);
      s0 = mfma16(ka0, qf[0], z);
      s0 = mfma16(ka1, qf[1], s0);
      s0 = mfma16(ka2, qf[2], s0);
      s0 = mfma16(ka3, qf[3], s0);
      __builtin_amdgcn_s_setprio(0);
    }

    // ---- phase 2: QK for s1 (regions 4-7) interleaved with exp(s0) ----
    {
      f32x16 z = {};
#pragma unroll
      for (int kst = 0; kst < 4; ++kst) {
        bf16x8 kc = *(const bf16x8*)(kb + ((4 + kst) * 1024) + fs);
        s1 = mfma16(kc, qf[kst], kst == 0 ? z : s1);
#pragma unroll
        for (int j = 0; j < 4; ++j) {
          int r = kst * 4 + j;
          float p = __builtin_amdgcn_exp2f(s0[r]);
          s0[r] = p;
          ls[r & 3] += p;
        }
      }
    }

    // ---- phase 3: PV0 (pf from s0 lo) || exp(s1 lo) ----
    {
      bf16x8 v0 = *(const bf16x8*)(kb + 8192 + 0 * 1024 + fs);
      bf16x8 v1 = *(const bf16x8*)(kb + 8192 + 4 * 1024 + fs);
      bf16x8 pf;
#pragma unroll
      for (int j = 0; j < 8; ++j) pf[j] = (bf16)s0[j];
      __builtin_amdgcn_s_setprio(1);
      o[0] = mfma16(v0, pf, o[0]);
      o[1] = mfma16(v1, pf, o[1]);
      __builtin_amdgcn_s_setprio(0);
#pragma unroll
      for (int j = 0; j < 8; ++j) {
        float p = __builtin_amdgcn_exp2f(s1[j]);
        s1[j] = p;
        ls[j & 3] += p;
      }
    }

    // ---- phase 4: PV1 (pf from s0 hi) || exp(s1 hi) ----
    {
      bf16x8 v0 = *(const bf16x8*)(kb + 8192 + 1 * 1024 + fs);
      bf16x8 v1 = *(const bf16x8*)(kb + 8192 + 5 * 1024 + fs);
      bf16x8 pf;
#pragma unroll
      for (int j = 0; j < 8; ++j) pf[j] = (bf16)s0[8 + j];
      __builtin_amdgcn_s_setprio(1);
      o[0] = mfma16(v0, pf, o[0]);
      o[1] = mfma16(v1, pf, o[1]);
      __builtin_amdgcn_s_setprio(0);
#pragma unroll
      for (int j = 0; j < 8; ++j) {
        float p = __builtin_amdgcn_exp2f(s1[8 + j]);
        s1[8 + j] = p;
        ls[j & 3] += p;
      }
    }

    // ---- phase 5: PV2, PV3 (pf from s1) ----
#pragma unroll
    for (int kst = 2; kst < 4; ++kst) {
      bf16x8 v0 = *(const bf16x8*)(kb + 8192 + (kst * 1024) + fs);
      bf16x8 v1 = *(const bf16x8*)(kb + 8192 + ((4 + kst) * 1024) + fs);
      int rbase = (kst & 1) * 8;
      bf16x8 pf;
#pragma unroll
      for (int j = 0; j < 8; ++j) pf[j] = (bf16)s1[rbase + j];
      __builtin_amdgcn_s_setprio(1);
      o[0] = mfma16(v0, pf, o[0]);
      o[1] = mfma16(v1, pf, o[1]);
      __builtin_amdgcn_s_setprio(0);
    }

    // all waves done READING kb -> safe to overwrite with tile t+2
    __builtin_amdgcn_s_barrier();
    if (t + 2 < 16) stage(t + 2, kb);
  }

  // ---- combine halves through LDS (exact f32 add), then normalize ----
  float lsum = (ls[0] + ls[1]) + (ls[2] + ls[3]);
  float lcol = lsum + __shfl_xor(lsum, 32);  // per-col l of this half
  if (half) {
    float* dstO = (float*)smem + pair * 2112;   // stride 33 dwords: bank-free
    for (int di = 0; di < 2; ++di)
      for (int r = 0; r < 16; ++r) dstO[L * 33 + di * 16 + r] = o[di][r];
    if (h5 == 0) ((float*)(smem + 33792))[pair * 32 + l31] = lcol;
  }
  __syncthreads();
  float linv = 0.f;
  if (!half) {
    float* srcO = (float*)smem + pair * 2112;
    for (int di = 0; di < 2; ++di)
      for (int r = 0; r < 16; ++r) o[di][r] += srcO[L * 33 + di * 16 + r];
    float lother = ((float*)(smem + 33792))[pair * 32 + l31];
    linv = 1.f / (lcol + lother);
  }
  __syncthreads();
  if (!half) {
    // O^T/l -> per-wave LDS tile [32 q][68 d-stride] -> coalesced store
    char* ot = smem + pair * 4352;
    for (int di = 0; di < 2; ++di)
      for (int g = 0; g < 4; ++g) {
        bf16x4 pk;
        for (int r = 0; r < 4; ++r)
          pk[r] = (bf16)(o[di][g * 4 + r] * linv);
        int d0 = di * 32 + g * 8 + h5 * 4;
        *(bf16x4*)(ot + (l31 * 68 + d0) * 2) = pk;
      }
    for (int i = 0; i < 4; ++i) {
      int qloc = (L >> 3) + i * 8;
      int cc = L & 7;
      bf16x8 vv = *(const bf16x8*)(ot + (qloc * 68 + cc * 8) * 2);
      *(bf16x8*)(Ob + (long)(b * 2048 + q0 + qloc) * 1024 + h * 64 + cc * 8) = vv;
    }
  }
}

// ---------------------------------------------------------------------------
extern "C" void kernel_launch(void* const* d_in, const int* in_sizes, int n_in,
                              void* d_out, int out_size, void* d_ws, size_t ws_size,
                              hipStream_t stream) {
  const float* x   = (const float*)d_in[0];
  const float* Wq  = (const float*)d_in[1];
  const float* bq  = (const float*)d_in[2];
  const float* Wk  = (const float*)d_in[3];
  const float* bk  = (const float*)d_in[4];
  const float* Wv  = (const float*)d_in[5];
  const float* bv  = (const float*)d_in[6];
  const float* Wp  = (const float*)d_in[7];
  const float* bp  = (const float*)d_in[8];
  const float* lq1 = (const float*)d_in[9];
  const float* lk1 = (const float*)d_in[10];
  const float* lq2 = (const float*)d_in[11];
  const float* lk2 = (const float*)d_in[12];
  float* out = (float*)d_out;

  // ws layout: pad | xb(8MB) | Wqkv(6MB) | Wpb(2MB) | Vt(8MB) | Ob(8MB)
  char* ws = (char*)d_ws;
  bf16* xb   = (bf16*)(ws + 1024);
  bf16* Wqkv = xb + (long)4096 * 1024;
  bf16* Wpb  = Wqkv + (long)3 * 1024 * 1024;
  bf16* Vt   = Wpb + (long)1024 * 1024;       // [32 bh][64 d][2048 slot]
  bf16* Ob   = Vt + (long)4096 * 1024;
  // Q/K bf16 tensors live in d_out (16MB); dead before final GEMM writes it
  bf16* Qb = (bf16*)d_out;
  bf16* Kb = Qb + (long)4096 * 1024;

  cast5_kernel<<<dim3(4096), 256, 0, stream>>>(
      x, Wq, Wk, Wv, Wp, lq1, lk1, lq2, lk2, xb, Wqkv, Wpb);
  gemm_qkv_kernel<<<dim3(32, 24), 256, 0, stream>>>(
      xb, Wqkv, bq, bk, bv, Qb, Kb, Vt);
  attn_kernel<<<dim3(32, 16), 512, 0, stream>>>(Qb, Kb, Vt, Ob);
  gemm_proj_kernel<<<dim3(32, 8), 256, 0, stream>>>(Ob, Wpb, bp, out);
}

// Round 12
// 204.839 us; speedup vs baseline: 1.0244x; 1.0056x over previous
//
#include <hip/hip_runtime.h>

typedef __bf16 bf16;
typedef __bf16 bf16x8 __attribute__((ext_vector_type(8)));
typedef __bf16 bf16x4 __attribute__((ext_vector_type(4)));
typedef float  f32x16 __attribute__((ext_vector_type(16)));
typedef unsigned int uint;
typedef unsigned int uintx4 __attribute__((ext_vector_type(4)));

#define QSCALE (0.125f * 1.44269504088896340736f)   // 1/sqrt(64) * log2(e), folded into Q

__device__ __forceinline__ void g2l16(const void* g, void* l) {
  __builtin_amdgcn_global_load_lds(
      (const __attribute__((address_space(1))) void*)g,
      (__attribute__((address_space(3))) void*)l, 16, 0, 0);
}

__device__ __forceinline__ f32x16 mfma16(bf16x8 a, bf16x8 b, f32x16 c) {
  return __builtin_amdgcn_mfma_f32_32x32x16_bf16(a, b, c, 0, 0, 0);
}

// ---------------------------------------------------------------------------
// Session invariants (measured over 12 rounds):
//  - attn v5 body sits EXACTLY at the 128-VGPR cap: any widened live range
//    (early V frags, ladd f32x16, s0/s1 interleave) spills. Spill tripwire =
//    FETCH/WRITE balloon (VGPR_Count stays 64 and lies).
//  - LDS slot map must keep lane pairs contiguous in global (g2l16 staging
//    coalescing); the resulting 2-way read bank-alias is free (m136).
//    Conflict-free reads are structurally incompatible with global_load_lds.
//  - 16 waves/CU is invariant (512thr x 2blk == 256thr x 4blk).
//  - Counted-vmcnt staging depth beyond 1 tile: null on this 2-barrier loop.
// ---------------------------------------------------------------------------

// ---------------------------------------------------------------------------
// f32 -> bf16 casts. seg0: x; seg1..3: Wq/Wk/Wv -> Wqkv; seg4: Wp -> Wpb with
// the differential-combine folded into the weight:
//   Wpb[n,k]      = Wp[n,k]                      (k < 512)
//   Wpb[n,512+j]  = Wp[n,512+j] - lv*Wp[n,j]     (j < 512)
// lv recomputed inline per seg-4 wave (tiny reduction; saves a kernel).
// ---------------------------------------------------------------------------
__global__ void cast5_kernel(const float* __restrict__ x,
                             const float* __restrict__ wq, const float* __restrict__ wk,
                             const float* __restrict__ wv, const float* __restrict__ wp,
                             const float* __restrict__ lq1, const float* __restrict__ lk1,
                             const float* __restrict__ lq2, const float* __restrict__ lk2,
                             bf16* __restrict__ xb, bf16* __restrict__ wqkv,
                             bf16* __restrict__ wpb) {
  int bx = blockIdx.x;
  int seg, idx;
  if (bx < 2048) { seg = 0; idx = bx; }
  else { int t = bx - 2048; seg = 1 + (t >> 9); idx = t & 511; }
  long i = (long)(idx * 256 + threadIdx.x) * 8;
  const float* s; bf16* d;
  if (seg == 0)      { s = x;  d = xb; }
  else if (seg == 1) { s = wq; d = wqkv; }
  else if (seg == 2) { s = wk; d = wqkv + 1048576; }
  else if (seg == 3) { s = wv; d = wqkv + 2097152; }
  else               { s = wp; d = wpb; }
  float4 f0 = *(const float4*)(s + i);
  float4 f1 = *(const float4*)(s + i + 4);
  if (seg == 4 && (i & 1023) >= 512) {
    int t = threadIdx.x & 63;
    float accum = 0.f;
    for (int hh = 0; hh < 8; ++hh) {
      float v1 = lq1[hh*64 + t] * lk1[hh*64 + t];
      float v2 = lq2[hh*64 + t] * lk2[hh*64 + t];
      for (int off = 32; off; off >>= 1) {
        v1 += __shfl_xor(v1, off);
        v2 += __shfl_xor(v2, off);
      }
      accum += expf(fminf(v1, 5.f)) - expf(fminf(v2, 5.f));
    }
    float lv = accum / 8.f + 0.8f;
    float4 g0 = *(const float4*)(s + i - 512);
    float4 g1 = *(const float4*)(s + i - 508);
    f0.x -= lv * g0.x; f0.y -= lv * g0.y; f0.z -= lv * g0.z; f0.w -= lv * g0.w;
    f1.x -= lv * g1.x; f1.y -= lv * g1.y; f1.z -= lv * g1.z; f1.w -= lv * g1.w;
  }
  bf16x8 o;
  o[0] = (bf16)f0.x; o[1] = (bf16)f0.y; o[2] = (bf16)f0.z; o[3] = (bf16)f0.w;
  o[4] = (bf16)f1.x; o[5] = (bf16)f1.y; o[6] = (bf16)f1.z; o[7] = (bf16)f1.w;
  *(bf16x8*)(d + i) = o;
}

// ---------------------------------------------------------------------------
// QKV fused NT GEMM: 128x128 tile, BK=64. grid (32, 24); by = nblk>>3 picks
// Q/K/V. Q scaled by QSCALE. V written transposed AND key-permuted into
// Vt[bh][d][slot]: within each 64-token tile, token tau = 8*Qp + 4*h5 + r
// goes to slot = 16*(Qp>>1) + 8*h5 + 4*(Qp&1) + r.  This permutation makes
// the attention PV B-fragment equal each lane's own 8 consecutive S-regs
// (no cross-lane shuffles) while A-fragment reads stay unchanged.
// V epilogue goes through a padded LDS tile so global stores are
// row-contiguous (256B/instr coalesced) instead of 8B x 32-line scatter.
// ---------------------------------------------------------------------------
__global__ __launch_bounds__(256, 2) void gemm_qkv_kernel(
    const bf16* __restrict__ A, const bf16* __restrict__ B,
    const float* __restrict__ bias0, const float* __restrict__ bias1,
    const float* __restrict__ bias2,
    bf16* __restrict__ O0, bf16* __restrict__ O1, bf16* __restrict__ O2) {
  __shared__ __align__(16) char smem[34 * 1024];   // K-loop uses 32KB; V-epi 33KB
  const int tid = threadIdx.x;
  const int w = tid >> 6, L = tid & 63;
  const int l31 = L & 31, h5 = L >> 5;
  const int m0 = blockIdx.x * 128;
  const int n0g = blockIdx.y * 128;
  const int by = n0g >> 10;
  const bf16* Bp = B + (long)by * 1048576;
  const float* biasp = (by == 0) ? bias0 : ((by == 1) ? bias1 : bias2);
  const int nloc = n0g & 1023;

  f32x16 acc[2][2];
  for (int i = 0; i < 2; ++i) for (int j = 0; j < 2; ++j)
    for (int r = 0; r < 16; ++r) acc[i][j][r] = 0.f;

  const int srow = L >> 1, spar = L & 1;
  const int wm = w >> 1, wn = w & 1;
  const int fs = (l31 * 2 + h5) * 16;

  for (int k0 = 0; k0 < 1024; k0 += 64) {
    for (int i = 0; i < 8; ++i) {
      int r = w * 8 + i;
      int rr = r & 15;
      int rowblk = rr >> 2, kst = rr & 3;
      int row = rowblk * 32 + srow;
      int kk = k0 + (kst * 2 + spar) * 8;
      const bf16* gsrc = (r < 16) ? (A + (long)(m0 + row) * 1024 + kk)
                                  : (Bp + (long)(nloc + row) * 1024 + kk);
      g2l16(gsrc, smem + r * 1024);
    }
    __syncthreads();
    for (int kst = 0; kst < 4; ++kst) {
      bf16x8 a0 = *(const bf16x8*)(smem + (((wm * 2 + 0) * 4 + kst) * 1024) + fs);
      bf16x8 a1 = *(const bf16x8*)(smem + (((wm * 2 + 1) * 4 + kst) * 1024) + fs);
      bf16x8 b0 = *(const bf16x8*)(smem + 16384 + (((wn * 2 + 0) * 4 + kst) * 1024) + fs);
      bf16x8 b1 = *(const bf16x8*)(smem + 16384 + (((wn * 2 + 1) * 4 + kst) * 1024) + fs);
      acc[0][0] = mfma16(a0, b0, acc[0][0]);
      acc[0][1] = mfma16(a0, b1, acc[0][1]);
      acc[1][0] = mfma16(a1, b0, acc[1][0]);
      acc[1][1] = mfma16(a1, b1, acc[1][1]);
    }
    __syncthreads();
  }

  if (by == 2) {
    // ---- V epilogue via LDS bounce ----
    bf16* vt = (bf16*)smem;
    int b = m0 >> 11;
    int nbase = (m0 & 2047);
    for (int mi = 0; mi < 2; ++mi) for (int ni = 0; ni < 2; ++ni) {
      int lcol = wn * 64 + ni * 32 + l31;
      float bias_v = biasp[nloc + lcol];
      for (int g = 0; g < 4; ++g) {
        bf16x4 pk;
        for (int r = 0; r < 4; ++r) pk[r] = (bf16)(acc[mi][ni][g * 4 + r] + bias_v);
        int Qp = mi * 4 + g;
        int lslot = wm * 64 + (Qp >> 1) * 16 + h5 * 8 + (Qp & 1) * 4;
        *(bf16x4*)(vt + lcol * 132 + lslot) = pk;
      }
    }
    __syncthreads();
    for (int rr = 0; rr < 32; ++rr) {
      int lcol = w * 32 + rr;
      int col = nloc + lcol;
      int hh = col >> 6, d = col & 63;
      uint val = *(const uint*)(vt + lcol * 132 + L * 2);
      *(uint*)(O2 + ((long)(b * 16 + hh) * 64 + d) * 2048 + nbase + L * 2) = val;
    }
  } else {
    bf16* dst = (by == 0) ? O0 : O1;
    float scale = (by == 0) ? QSCALE : 1.0f;
    for (int mi = 0; mi < 2; ++mi) for (int ni = 0; ni < 2; ++ni) {
      int col = nloc + wn * 64 + ni * 32 + l31;
      float bias_v = biasp[col];
      int row_base = m0 + wm * 64 + mi * 32 + 4 * h5;
      for (int reg = 0; reg < 16; ++reg) {
        int rowoff = (reg & 3) + 8 * (reg >> 2);
        float v = (acc[mi][ni][reg] + bias_v) * scale;
        dst[(long)(row_base + rowoff) * 1024 + col] = (bf16)v;
      }
    }
  }
}

// ---------------------------------------------------------------------------
// Projection GEMM: 128x128 tile, clone of the proven gemm_qkv loop, f32 out
// + bias. grid (32,8) = 256 blocks.
// ---------------------------------------------------------------------------
__global__ __launch_bounds__(256, 2) void gemm_proj_kernel(
    const bf16* __restrict__ A, const bf16* __restrict__ B,
    const float* __restrict__ bias, float* __restrict__ Of) {
  __shared__ __align__(16) char smem[32 * 1024];
  const int tid = threadIdx.x;
  const int w = tid >> 6, L = tid & 63;
  const int l31 = L & 31, h5 = L >> 5;
  const int m0 = blockIdx.x * 128;
  const int n0 = blockIdx.y * 128;

  f32x16 acc[2][2];
  for (int i = 0; i < 2; ++i) for (int j = 0; j < 2; ++j)
    for (int r = 0; r < 16; ++r) acc[i][j][r] = 0.f;

  const int srow = L >> 1, spar = L & 1;
  const int wm = w >> 1, wn = w & 1;
  const int fs = (l31 * 2 + h5) * 16;

  for (int k0 = 0; k0 < 1024; k0 += 64) {
    for (int i = 0; i < 8; ++i) {
      int r = w * 8 + i;
      int rr = r & 15;
      int rowblk = rr >> 2, kst = rr & 3;
      int row = rowblk * 32 + srow;
      int kk = k0 + (kst * 2 + spar) * 8;
      const bf16* gsrc = (r < 16) ? (A + (long)(m0 + row) * 1024 + kk)
                                  : (B + (long)(n0 + row) * 1024 + kk);
      g2l16(gsrc, smem + r * 1024);
    }
    __syncthreads();
    for (int kst = 0; kst < 4; ++kst) {
      bf16x8 a0 = *(const bf16x8*)(smem + (((wm * 2 + 0) * 4 + kst) * 1024) + fs);
      bf16x8 a1 = *(const bf16x8*)(smem + (((wm * 2 + 1) * 4 + kst) * 1024) + fs);
      bf16x8 b0 = *(const bf16x8*)(smem + 16384 + (((wn * 2 + 0) * 4 + kst) * 1024) + fs);
      bf16x8 b1 = *(const bf16x8*)(smem + 16384 + (((wn * 2 + 1) * 4 + kst) * 1024) + fs);
      acc[0][0] = mfma16(a0, b0, acc[0][0]);
      acc[0][1] = mfma16(a0, b1, acc[0][1]);
      acc[1][0] = mfma16(a1, b0, acc[1][0]);
      acc[1][1] = mfma16(a1, b1, acc[1][1]);
    }
    __syncthreads();
  }

  for (int mi = 0; mi < 2; ++mi) for (int ni = 0; ni < 2; ++ni) {
    int col = n0 + wn * 64 + ni * 32 + l31;
    float bias_v = bias[col];
    int row_base = m0 + wm * 64 + mi * 32 + 4 * h5;
    for (int reg = 0; reg < 16; ++reg) {
      int rowoff = (reg & 3) + 8 * (reg >> 2);
      Of[(long)(row_base + rowoff) * 1024 + col] = acc[mi][ni][reg] + bias_v;
    }
  }
}

// ---------------------------------------------------------------------------
// Flash attention, intra-block K-split (64-key tiles, 16 iters). grid
// (32 bh, 16 qt), 512 thr = 8 waves: waves 0-3 keys 0..1023, waves 4-7 keys
// 1024..2047; wave pair (w, w+4) shares a 32-query range. Fixed-reference
// softmax (p = exp2(s)); halves combined through LDS (f32) at the end.
// Vt is key-permuted (see gemm_qkv_kernel), so the PV B-fragment is each
// lane's own 8 consecutive S-regs: zero cross-lane ops in the K-loop.
//
// ANCHOR (v5): proven 47.7-50.0us across machines, no spill. All variants
// rejected with counter evidence: v2-depth (null), v3/v4/v9/v12 (spill),
// v6 (uncoalesced V), v8 (staging decoalesce), v11 (occupancy invariant).
// ---------------------------------------------------------------------------
__global__ __launch_bounds__(512, 4) void attn_kernel(
    const bf16* __restrict__ Qb, const bf16* __restrict__ Kb,
    const bf16* __restrict__ Vt, bf16* __restrict__ Ob) {
  // staging: buf{0,1} x [half][K 8KB | V 8KB] = 64KB.  epilogue (reuses the
  // same bytes after the loop): O-exchange 4 pairs x 8448B = 33792,
  // l at 33792..34304, transpose 4x4352.
  __shared__ __align__(16) char smem[65536];
  const int tid = threadIdx.x, w = tid >> 6, L = tid & 63;
  const int half = w >> 2, pair = w & 3;
  const int bh = blockIdx.x, qt = blockIdx.y;
  const int b = bh >> 4, h = bh & 15;
  const int q0 = qt * 128 + pair * 32;
  const int l31 = L & 31, h5 = L >> 5;
  const int srow = L >> 1, spar = L & 1;
  const int fs = (l31 * 2 + h5) * 16;

  // Q fragments (B-operand of S^T mfma), resident for the whole K loop
  bf16x8 qf[4];
  for (int kst = 0; kst < 4; ++kst)
    qf[kst] = *(const bf16x8*)(Qb + (long)(b * 2048 + q0 + l31) * 1024 + h * 64
                               + kst * 16 + h5 * 8);

  f32x16 o[2];  // [di] : O^T rows d, cols q (unnormalized partial)
  for (int i = 0; i < 2; ++i)
    for (int r = 0; r < 16; ++r) o[i][r] = 0.f;
  float ls[4] = {0.f, 0.f, 0.f, 0.f};  // 4-way partial l

  const bf16* Kbh = Kb + (long)b * 2048 * 1024 + h * 64 + (long)half * 1024 * 1024;
  const bf16* Vth = Vt + (long)bh * 64 * 2048 + half * 1024;

  char* kb0 = smem + half * 16384;            // buffer 0 (this half)
  char* kb1 = smem + 32768 + half * 16384;    // buffer 1 (this half)

  // stage tile t into buffer kb: 4 global_load_lds per wave, 16 regions/half
  auto stage = [&](int t, char* kb) {
    int n0 = t * 64;
    for (int i = 0; i < 4; ++i) {
      int r = pair * 4 + i;
      if (r < 8) {
        int nkb = r >> 2, kst = r & 3;
        const bf16* g = Kbh + (long)(n0 + nkb * 32 + srow) * 1024 + (kst * 2 + spar) * 8;
        g2l16(g, kb + r * 1024);
      } else {
        int rr = r - 8, db = rr >> 2, kst = rr & 3;
        const bf16* g = Vth + (long)(db * 32 + srow) * 2048 + n0 + (kst * 2 + spar) * 8;
        g2l16(g, kb + 8192 + rr * 1024);
      }
    }
  };

  stage(0, kb0);   // 4 loads in flight
  stage(1, kb1);   // 8 loads in flight

  for (int t = 0; t < 16; ++t) {
    char* kb = (t & 1) ? kb1 : kb0;
    // wait for THIS tile's stage (the 4 oldest); leave next tile's in flight
    if (t < 15) asm volatile("s_waitcnt vmcnt(4)" ::: "memory");
    else        asm volatile("s_waitcnt vmcnt(0)" ::: "memory");
    __builtin_amdgcn_s_barrier();

    // S^T[key][q]; zero-C folded into kst=0
    f32x16 s[2];
    {
      bf16x8 k0f = *(const bf16x8*)(kb + fs);
      bf16x8 k1f = *(const bf16x8*)(kb + 4 * 1024 + fs);
      f32x16 z = {};
      __builtin_amdgcn_s_setprio(1);
      s[0] = mfma16(k0f, qf[0], z);
      s[1] = mfma16(k1f, qf[0], z);
      __builtin_amdgcn_s_setprio(0);
    }
    for (int kst = 1; kst < 4; ++kst) {
      bf16x8 k0f = *(const bf16x8*)(kb + (kst * 1024) + fs);
      bf16x8 k1f = *(const bf16x8*)(kb + ((4 + kst) * 1024) + fs);
      __builtin_amdgcn_s_setprio(1);
      s[0] = mfma16(k0f, qf[kst], s[0]);
      s[1] = mfma16(k1f, qf[kst], s[1]);
      __builtin_amdgcn_s_setprio(0);
    }

    // p = exp2(s); accumulate l into 4 partials
    for (int nki = 0; nki < 2; ++nki)
      for (int r = 0; r < 16; ++r) {
        float p = __builtin_amdgcn_exp2f(s[nki][r]);
        s[nki][r] = p;
        ls[r & 3] += p;
      }

    // O^T += Vt_tile · P^T.  Vt global layout is key-permuted so that the
    // B-fragment for kst is exactly s[kst>>1][8*(kst&1) + 0..7] in order.
    for (int kst = 0; kst < 4; ++kst) {
      bf16x8 v0 = *(const bf16x8*)(kb + 8192 + (kst * 1024) + fs);
      bf16x8 v1 = *(const bf16x8*)(kb + 8192 + ((4 + kst) * 1024) + fs);
      int nki = kst >> 1;
      int rbase = (kst & 1) * 8;
      bf16x8 pf;   // direct casts -> v_cvt_pk_bf16_f32 pairs (m240)
#pragma unroll
      for (int j = 0; j < 8; ++j) pf[j] = (bf16)s[nki][rbase + j];
      __builtin_amdgcn_s_setprio(1);
      o[0] = mfma16(v0, pf, o[0]);
      o[1] = mfma16(v1, pf, o[1]);
      __builtin_amdgcn_s_setprio(0);
    }

    // all waves done READING kb -> safe to overwrite with tile t+2
    __builtin_amdgcn_s_barrier();
    if (t + 2 < 16) stage(t + 2, kb);
  }

  // ---- combine halves through LDS (exact f32 add), then normalize ----
  float lsum = (ls[0] + ls[1]) + (ls[2] + ls[3]);
  float lcol = lsum + __shfl_xor(lsum, 32);  // per-col l of this half
  if (half) {
    float* dstO = (float*)smem + pair * 2112;   // stride 33 dwords: bank-free
    for (int di = 0; di < 2; ++di)
      for (int r = 0; r < 16; ++r) dstO[L * 33 + di * 16 + r] = o[di][r];
    if (h5 == 0) ((float*)(smem + 33792))[pair * 32 + l31] = lcol;
  }
  __syncthreads();
  float linv = 0.f;
  if (!half) {
    float* srcO = (float*)smem + pair * 2112;
    for (int di = 0; di < 2; ++di)
      for (int r = 0; r < 16; ++r) o[di][r] += srcO[L * 33 + di * 16 + r];
    float lother = ((float*)(smem + 33792))[pair * 32 + l31];
    linv = 1.f / (lcol + lother);
  }
  __syncthreads();
  if (!half) {
    // O^T/l -> per-wave LDS tile [32 q][68 d-stride] -> coalesced store
    char* ot = smem + pair * 4352;
    for (int di = 0; di < 2; ++di)
      for (int g = 0; g < 4; ++g) {
        bf16x4 pk;
        for (int r = 0; r < 4; ++r)
          pk[r] = (bf16)(o[di][g * 4 + r] * linv);
        int d0 = di * 32 + g * 8 + h5 * 4;
        *(bf16x4*)(ot + (l31 * 68 + d0) * 2) = pk;
      }
    for (int i = 0; i < 4; ++i) {
      int qloc = (L >> 3) + i * 8;
      int cc = L & 7;
      bf16x8 vv = *(const bf16x8*)(ot + (qloc * 68 + cc * 8) * 2);
      *(bf16x8*)(Ob + (long)(b * 2048 + q0 + qloc) * 1024 + h * 64 + cc * 8) = vv;
    }
  }
}

// ---------------------------------------------------------------------------
extern "C" void kernel_launch(void* const* d_in, const int* in_sizes, int n_in,
                              void* d_out, int out_size, void* d_ws, size_t ws_size,
                              hipStream_t stream) {
  const float* x   = (const float*)d_in[0];
  const float* Wq  = (const float*)d_in[1];
  const float* bq  = (const float*)d_in[2];
  const float* Wk  = (const float*)d_in[3];
  const float* bk  = (const float*)d_in[4];
  const float* Wv  = (const float*)d_in[5];
  const float* bv  = (const float*)d_in[6];
  const float* Wp  = (const float*)d_in[7];
  const float* bp  = (const float*)d_in[8];
  const float* lq1 = (const float*)d_in[9];
  const float* lk1 = (const float*)d_in[10];
  const float* lq2 = (const float*)d_in[11];
  const float* lk2 = (const float*)d_in[12];
  float* out = (float*)d_out;

  // ws layout: pad | xb(8MB) | Wqkv(6MB) | Wpb(2MB) | Vt(8MB) | Ob(8MB)
  char* ws = (char*)d_ws;
  bf16* xb   = (bf16*)(ws + 1024);
  bf16* Wqkv = xb + (long)4096 * 1024;
  bf16* Wpb  = Wqkv + (long)3 * 1024 * 1024;
  bf16* Vt   = Wpb + (long)1024 * 1024;       // [32 bh][64 d][2048 slot]
  bf16* Ob   = Vt + (long)4096 * 1024;
  // Q/K bf16 tensors live in d_out (16MB); dead before final GEMM writes it
  bf16* Qb = (bf16*)d_out;
  bf16* Kb = Qb + (long)4096 * 1024;

  cast5_kernel<<<dim3(4096), 256, 0, stream>>>(
      x, Wq, Wk, Wv, Wp, lq1, lk1, lq2, lk2, xb, Wqkv, Wpb);
  gemm_qkv_kernel<<<dim3(32, 24), 256, 0, stream>>>(
      xb, Wqkv, bq, bk, bv, Qb, Kb, Vt);
  attn_kernel<<<dim3(32, 16), 512, 0, stream>>>(Qb, Kb, Vt, Ob);
  gemm_proj_kernel<<<dim3(32, 8), 256, 0, stream>>>(Ob, Wpb, bp, out);
}

// Round 13
// 204.451 us; speedup vs baseline: 1.0263x; 1.0019x over previous
//
#include <hip/hip_runtime.h>

typedef __bf16 bf16;
typedef __bf16 bf16x8 __attribute__((ext_vector_type(8)));
typedef __bf16 bf16x4 __attribute__((ext_vector_type(4)));
typedef float  f32x16 __attribute__((ext_vector_type(16)));
typedef unsigned int uint;
typedef unsigned int uintx4 __attribute__((ext_vector_type(4)));

#define QSCALE (0.125f * 1.44269504088896340736f)   // 1/sqrt(64) * log2(e), folded into Q

__device__ __forceinline__ void g2l16(const void* g, void* l) {
  __builtin_amdgcn_global_load_lds(
      (const __attribute__((address_space(1))) void*)g,
      (__attribute__((address_space(3))) void*)l, 16, 0, 0);
}

__device__ __forceinline__ f32x16 mfma16(bf16x8 a, bf16x8 b, f32x16 c) {
  return __builtin_amdgcn_mfma_f32_32x32x16_bf16(a, b, c, 0, 0, 0);
}

// ---------------------------------------------------------------------------
// Session invariants (measured over 13 rounds):
//  - the 8-wave/32q attn body sits EXACTLY at the 128-VGPR cap: any widened
//    live range spills. Spill tripwire = FETCH/WRITE balloon.
//  - LDS slot map must keep lane pairs contiguous in global (g2l16 staging
//    coalescing); the 2-way read bank-alias costs +4cyc/b128 (measured).
//  - 16 waves/CU at 128-cap is invariant under block repartition.
//  - LDS pipe is the top pipe (~55%): 256 b128 reads/CU/iter, 4x tile
//    re-read duplication across waves. v13 attacks THIS: 64q/wave halves
//    reads/MFMA, paid for with the 256-VGPR budget (8 waves/CU).
// ---------------------------------------------------------------------------

// ---------------------------------------------------------------------------
// f32 -> bf16 casts. seg0: x; seg1..3: Wq/Wk/Wv -> Wqkv; seg4: Wp -> Wpb with
// the differential-combine folded into the weight:
//   Wpb[n,k]      = Wp[n,k]                      (k < 512)
//   Wpb[n,512+j]  = Wp[n,512+j] - lv*Wp[n,j]     (j < 512)
// lv recomputed inline per seg-4 wave (tiny reduction; saves a kernel).
// ---------------------------------------------------------------------------
__global__ void cast5_kernel(const float* __restrict__ x,
                             const float* __restrict__ wq, const float* __restrict__ wk,
                             const float* __restrict__ wv, const float* __restrict__ wp,
                             const float* __restrict__ lq1, const float* __restrict__ lk1,
                             const float* __restrict__ lq2, const float* __restrict__ lk2,
                             bf16* __restrict__ xb, bf16* __restrict__ wqkv,
                             bf16* __restrict__ wpb) {
  int bx = blockIdx.x;
  int seg, idx;
  if (bx < 2048) { seg = 0; idx = bx; }
  else { int t = bx - 2048; seg = 1 + (t >> 9); idx = t & 511; }
  long i = (long)(idx * 256 + threadIdx.x) * 8;
  const float* s; bf16* d;
  if (seg == 0)      { s = x;  d = xb; }
  else if (seg == 1) { s = wq; d = wqkv; }
  else if (seg == 2) { s = wk; d = wqkv + 1048576; }
  else if (seg == 3) { s = wv; d = wqkv + 2097152; }
  else               { s = wp; d = wpb; }
  float4 f0 = *(const float4*)(s + i);
  float4 f1 = *(const float4*)(s + i + 4);
  if (seg == 4 && (i & 1023) >= 512) {
    int t = threadIdx.x & 63;
    float accum = 0.f;
    for (int hh = 0; hh < 8; ++hh) {
      float v1 = lq1[hh*64 + t] * lk1[hh*64 + t];
      float v2 = lq2[hh*64 + t] * lk2[hh*64 + t];
      for (int off = 32; off; off >>= 1) {
        v1 += __shfl_xor(v1, off);
        v2 += __shfl_xor(v2, off);
      }
      accum += expf(fminf(v1, 5.f)) - expf(fminf(v2, 5.f));
    }
    float lv = accum / 8.f + 0.8f;
    float4 g0 = *(const float4*)(s + i - 512);
    float4 g1 = *(const float4*)(s + i - 508);
    f0.x -= lv * g0.x; f0.y -= lv * g0.y; f0.z -= lv * g0.z; f0.w -= lv * g0.w;
    f1.x -= lv * g1.x; f1.y -= lv * g1.y; f1.z -= lv * g1.z; f1.w -= lv * g1.w;
  }
  bf16x8 o;
  o[0] = (bf16)f0.x; o[1] = (bf16)f0.y; o[2] = (bf16)f0.z; o[3] = (bf16)f0.w;
  o[4] = (bf16)f1.x; o[5] = (bf16)f1.y; o[6] = (bf16)f1.z; o[7] = (bf16)f1.w;
  *(bf16x8*)(d + i) = o;
}

// ---------------------------------------------------------------------------
// QKV fused NT GEMM: 128x128 tile, BK=64. grid (32, 24); by = nblk>>3 picks
// Q/K/V. Q scaled by QSCALE. V written transposed AND key-permuted into
// Vt[bh][d][slot]: within each 64-token tile, token tau = 8*Qp + 4*h5 + r
// goes to slot = 16*(Qp>>1) + 8*h5 + 4*(Qp&1) + r.  This permutation makes
// the attention PV B-fragment equal each lane's own 8 consecutive S-regs
// (no cross-lane shuffles) while A-fragment reads stay unchanged.
// V epilogue goes through a padded LDS tile so global stores are
// row-contiguous (256B/instr coalesced) instead of 8B x 32-line scatter.
// ---------------------------------------------------------------------------
__global__ __launch_bounds__(256, 2) void gemm_qkv_kernel(
    const bf16* __restrict__ A, const bf16* __restrict__ B,
    const float* __restrict__ bias0, const float* __restrict__ bias1,
    const float* __restrict__ bias2,
    bf16* __restrict__ O0, bf16* __restrict__ O1, bf16* __restrict__ O2) {
  __shared__ __align__(16) char smem[34 * 1024];   // K-loop uses 32KB; V-epi 33KB
  const int tid = threadIdx.x;
  const int w = tid >> 6, L = tid & 63;
  const int l31 = L & 31, h5 = L >> 5;
  const int m0 = blockIdx.x * 128;
  const int n0g = blockIdx.y * 128;
  const int by = n0g >> 10;
  const bf16* Bp = B + (long)by * 1048576;
  const float* biasp = (by == 0) ? bias0 : ((by == 1) ? bias1 : bias2);
  const int nloc = n0g & 1023;

  f32x16 acc[2][2];
  for (int i = 0; i < 2; ++i) for (int j = 0; j < 2; ++j)
    for (int r = 0; r < 16; ++r) acc[i][j][r] = 0.f;

  const int srow = L >> 1, spar = L & 1;
  const int wm = w >> 1, wn = w & 1;
  const int fs = (l31 * 2 + h5) * 16;

  for (int k0 = 0; k0 < 1024; k0 += 64) {
    for (int i = 0; i < 8; ++i) {
      int r = w * 8 + i;
      int rr = r & 15;
      int rowblk = rr >> 2, kst = rr & 3;
      int row = rowblk * 32 + srow;
      int kk = k0 + (kst * 2 + spar) * 8;
      const bf16* gsrc = (r < 16) ? (A + (long)(m0 + row) * 1024 + kk)
                                  : (Bp + (long)(nloc + row) * 1024 + kk);
      g2l16(gsrc, smem + r * 1024);
    }
    __syncthreads();
    for (int kst = 0; kst < 4; ++kst) {
      bf16x8 a0 = *(const bf16x8*)(smem + (((wm * 2 + 0) * 4 + kst) * 1024) + fs);
      bf16x8 a1 = *(const bf16x8*)(smem + (((wm * 2 + 1) * 4 + kst) * 1024) + fs);
      bf16x8 b0 = *(const bf16x8*)(smem + 16384 + (((wn * 2 + 0) * 4 + kst) * 1024) + fs);
      bf16x8 b1 = *(const bf16x8*)(smem + 16384 + (((wn * 2 + 1) * 4 + kst) * 1024) + fs);
      acc[0][0] = mfma16(a0, b0, acc[0][0]);
      acc[0][1] = mfma16(a0, b1, acc[0][1]);
      acc[1][0] = mfma16(a1, b0, acc[1][0]);
      acc[1][1] = mfma16(a1, b1, acc[1][1]);
    }
    __syncthreads();
  }

  if (by == 2) {
    // ---- V epilogue via LDS bounce ----
    bf16* vt = (bf16*)smem;
    int b = m0 >> 11;
    int nbase = (m0 & 2047);
    for (int mi = 0; mi < 2; ++mi) for (int ni = 0; ni < 2; ++ni) {
      int lcol = wn * 64 + ni * 32 + l31;
      float bias_v = biasp[nloc + lcol];
      for (int g = 0; g < 4; ++g) {
        bf16x4 pk;
        for (int r = 0; r < 4; ++r) pk[r] = (bf16)(acc[mi][ni][g * 4 + r] + bias_v);
        int Qp = mi * 4 + g;
        int lslot = wm * 64 + (Qp >> 1) * 16 + h5 * 8 + (Qp & 1) * 4;
        *(bf16x4*)(vt + lcol * 132 + lslot) = pk;
      }
    }
    __syncthreads();
    for (int rr = 0; rr < 32; ++rr) {
      int lcol = w * 32 + rr;
      int col = nloc + lcol;
      int hh = col >> 6, d = col & 63;
      uint val = *(const uint*)(vt + lcol * 132 + L * 2);
      *(uint*)(O2 + ((long)(b * 16 + hh) * 64 + d) * 2048 + nbase + L * 2) = val;
    }
  } else {
    bf16* dst = (by == 0) ? O0 : O1;
    float scale = (by == 0) ? QSCALE : 1.0f;
    for (int mi = 0; mi < 2; ++mi) for (int ni = 0; ni < 2; ++ni) {
      int col = nloc + wn * 64 + ni * 32 + l31;
      float bias_v = biasp[col];
      int row_base = m0 + wm * 64 + mi * 32 + 4 * h5;
      for (int reg = 0; reg < 16; ++reg) {
        int rowoff = (reg & 3) + 8 * (reg >> 2);
        float v = (acc[mi][ni][reg] + bias_v) * scale;
        dst[(long)(row_base + rowoff) * 1024 + col] = (bf16)v;
      }
    }
  }
}

// ---------------------------------------------------------------------------
// Projection GEMM: 128x128 tile, clone of the proven gemm_qkv loop, f32 out
// + bias. grid (32,8) = 256 blocks.
// ---------------------------------------------------------------------------
__global__ __launch_bounds__(256, 2) void gemm_proj_kernel(
    const bf16* __restrict__ A, const bf16* __restrict__ B,
    const float* __restrict__ bias, float* __restrict__ Of) {
  __shared__ __align__(16) char smem[32 * 1024];
  const int tid = threadIdx.x;
  const int w = tid >> 6, L = tid & 63;
  const int l31 = L & 31, h5 = L >> 5;
  const int m0 = blockIdx.x * 128;
  const int n0 = blockIdx.y * 128;

  f32x16 acc[2][2];
  for (int i = 0; i < 2; ++i) for (int j = 0; j < 2; ++j)
    for (int r = 0; r < 16; ++r) acc[i][j][r] = 0.f;

  const int srow = L >> 1, spar = L & 1;
  const int wm = w >> 1, wn = w & 1;
  const int fs = (l31 * 2 + h5) * 16;

  for (int k0 = 0; k0 < 1024; k0 += 64) {
    for (int i = 0; i < 8; ++i) {
      int r = w * 8 + i;
      int rr = r & 15;
      int rowblk = rr >> 2, kst = rr & 3;
      int row = rowblk * 32 + srow;
      int kk = k0 + (kst * 2 + spar) * 8;
      const bf16* gsrc = (r < 16) ? (A + (long)(m0 + row) * 1024 + kk)
                                  : (B + (long)(n0 + row) * 1024 + kk);
      g2l16(gsrc, smem + r * 1024);
    }
    __syncthreads();
    for (int kst = 0; kst < 4; ++kst) {
      bf16x8 a0 = *(const bf16x8*)(smem + (((wm * 2 + 0) * 4 + kst) * 1024) + fs);
      bf16x8 a1 = *(const bf16x8*)(smem + (((wm * 2 + 1) * 4 + kst) * 1024) + fs);
      bf16x8 b0 = *(const bf16x8*)(smem + 16384 + (((wn * 2 + 0) * 4 + kst) * 1024) + fs);
      bf16x8 b1 = *(const bf16x8*)(smem + 16384 + (((wn * 2 + 1) * 4 + kst) * 1024) + fs);
      acc[0][0] = mfma16(a0, b0, acc[0][0]);
      acc[0][1] = mfma16(a0, b1, acc[0][1]);
      acc[1][0] = mfma16(a1, b0, acc[1][0]);
      acc[1][1] = mfma16(a1, b1, acc[1][1]);
    }
    __syncthreads();
  }

  for (int mi = 0; mi < 2; ++mi) for (int ni = 0; ni < 2; ++ni) {
    int col = n0 + wn * 64 + ni * 32 + l31;
    float bias_v = bias[col];
    int row_base = m0 + wm * 64 + mi * 32 + 4 * h5;
    for (int reg = 0; reg < 16; ++reg) {
      int rowoff = (reg & 3) + 8 * (reg >> 2);
      Of[(long)(row_base + rowoff) * 1024 + col] = acc[mi][ni][reg] + bias_v;
    }
  }
}

// ---------------------------------------------------------------------------
// Flash attention v13: LDS-traffic halving. grid (32 bh, 16 qt), 256 thr =
// 4 waves (2 halves x 2 subs). Each wave owns 64 q (subtiles A at q0,
// B at q0+32): every K/V-fragment ds_read feeds TWO MFMAs, halving per-CU
// LDS reads (the measured top pipe, ~55%). launch_bounds(256,2) -> 256-VGPR
// budget: peak live ~185 (o 64 + s 64 + qf 32 + misc) fits with headroom.
// 8 waves/CU (2/SIMD). Staging: sub-0 stages K (8 regions), sub-1 stages V;
// double-buffered, counted vmcnt(8). Same LDS slot map / barriers as anchor.
// ---------------------------------------------------------------------------
__global__ __launch_bounds__(256, 2) void attn_kernel(
    const bf16* __restrict__ Qb, const bf16* __restrict__ Kb,
    const bf16* __restrict__ Vt, bf16* __restrict__ Ob) {
  // staging: buf{0,1} x [half][K 8KB | V 8KB] = 64KB. epilogue reuses bytes:
  // O-exchange 4 vp x 8448B = 33792, l at 33792..34304, transpose 4x4352.
  __shared__ __align__(16) char smem[65536];
  const int tid = threadIdx.x, w = tid >> 6, L = tid & 63;
  const int half = w >> 1, sub = w & 1;
  const int bh = blockIdx.x, qt = blockIdx.y;
  const int b = bh >> 4, h = bh & 15;
  const int q0 = qt * 128 + sub * 64;
  const int l31 = L & 31, h5 = L >> 5;
  const int srow = L >> 1, spar = L & 1;
  const int fs = (l31 * 2 + h5) * 16;

  // Q fragments for both 32-q subtiles (resident all loop)
  bf16x8 qfA[4], qfB[4];
  for (int kst = 0; kst < 4; ++kst) {
    long qoff = (long)(b * 2048 + q0 + l31) * 1024 + h * 64 + kst * 16 + h5 * 8;
    qfA[kst] = *(const bf16x8*)(Qb + qoff);
    qfB[kst] = *(const bf16x8*)(Qb + qoff + 32 * 1024);
  }

  f32x16 oA[2], oB[2];  // O^T partials for subtiles A,B
  for (int i = 0; i < 2; ++i)
    for (int r = 0; r < 16; ++r) { oA[i][r] = 0.f; oB[i][r] = 0.f; }
  float lsA[4] = {0.f, 0.f, 0.f, 0.f};
  float lsB[4] = {0.f, 0.f, 0.f, 0.f};

  const bf16* Kbh = Kb + (long)b * 2048 * 1024 + h * 64 + (long)half * 1024 * 1024;
  const bf16* Vth = Vt + (long)bh * 64 * 2048 + half * 1024;

  char* kb0 = smem + half * 16384;
  char* kb1 = smem + 32768 + half * 16384;

  // sub-0 stages the 8 K regions; sub-1 the 8 V regions (8 g2l16 each)
  auto stage = [&](int t, char* kb) {
    int n0 = t * 64;
    if (sub == 0) {
      for (int r = 0; r < 8; ++r) {
        int nkb = r >> 2, kst = r & 3;
        const bf16* g = Kbh + (long)(n0 + nkb * 32 + srow) * 1024 + (kst * 2 + spar) * 8;
        g2l16(g, kb + r * 1024);
      }
    } else {
      for (int rr = 0; rr < 8; ++rr) {
        int db = rr >> 2, kst = rr & 3;
        const bf16* g = Vth + (long)(db * 32 + srow) * 2048 + n0 + (kst * 2 + spar) * 8;
        g2l16(g, kb + 8192 + rr * 1024);
      }
    }
  };

  stage(0, kb0);   // 8 loads in flight
  stage(1, kb1);   // 16 in flight

  for (int t = 0; t < 16; ++t) {
    char* kb = (t & 1) ? kb1 : kb0;
    // wait for THIS tile's 8 oldest; leave next tile's 8 in flight
    if (t < 15) asm volatile("s_waitcnt vmcnt(8)" ::: "memory");
    else        asm volatile("s_waitcnt vmcnt(0)" ::: "memory");
    __builtin_amdgcn_s_barrier();

    // S^T[key][q] for both subtiles; each K-frag read feeds 2 MFMAs
    f32x16 sA0, sA1, sB0, sB1;
    {
      bf16x8 k0f = *(const bf16x8*)(kb + fs);
      bf16x8 k1f = *(const bf16x8*)(kb + 4 * 1024 + fs);
      f32x16 z = {};
      __builtin_amdgcn_s_setprio(1);
      sA0 = mfma16(k0f, qfA[0], z);
      sA1 = mfma16(k1f, qfA[0], z);
      sB0 = mfma16(k0f, qfB[0], z);
      sB1 = mfma16(k1f, qfB[0], z);
      __builtin_amdgcn_s_setprio(0);
    }
#pragma unroll
    for (int kst = 1; kst < 4; ++kst) {
      bf16x8 k0f = *(const bf16x8*)(kb + (kst * 1024) + fs);
      bf16x8 k1f = *(const bf16x8*)(kb + ((4 + kst) * 1024) + fs);
      __builtin_amdgcn_s_setprio(1);
      sA0 = mfma16(k0f, qfA[kst], sA0);
      sA1 = mfma16(k1f, qfA[kst], sA1);
      sB0 = mfma16(k0f, qfB[kst], sB0);
      sB1 = mfma16(k1f, qfB[kst], sB1);
      __builtin_amdgcn_s_setprio(0);
    }

    // p = exp2(s); accumulate l partials per subtile
#pragma unroll
    for (int r = 0; r < 16; ++r) {
      float p0 = __builtin_amdgcn_exp2f(sA0[r]); sA0[r] = p0; lsA[r & 3] += p0;
      float p1 = __builtin_amdgcn_exp2f(sA1[r]); sA1[r] = p1; lsA[r & 3] += p1;
      float p2 = __builtin_amdgcn_exp2f(sB0[r]); sB0[r] = p2; lsB[r & 3] += p2;
      float p3 = __builtin_amdgcn_exp2f(sB1[r]); sB1[r] = p3; lsB[r & 3] += p3;
    }

    // O^T += Vt_tile · P^T; each V-frag read feeds 2 MFMAs
#pragma unroll
    for (int kst = 0; kst < 4; ++kst) {
      bf16x8 v0 = *(const bf16x8*)(kb + 8192 + (kst * 1024) + fs);
      bf16x8 v1 = *(const bf16x8*)(kb + 8192 + ((4 + kst) * 1024) + fs);
      int rbase = (kst & 1) * 8;
      bf16x8 pfA, pfB;
#pragma unroll
      for (int j = 0; j < 8; ++j) {
        pfA[j] = (bf16)((kst < 2) ? sA0[rbase + j] : sA1[rbase + j]);
        pfB[j] = (bf16)((kst < 2) ? sB0[rbase + j] : sB1[rbase + j]);
      }
      __builtin_amdgcn_s_setprio(1);
      oA[0] = mfma16(v0, pfA, oA[0]);
      oA[1] = mfma16(v1, pfA, oA[1]);
      oB[0] = mfma16(v0, pfB, oB[0]);
      oB[1] = mfma16(v1, pfB, oB[1]);
      __builtin_amdgcn_s_setprio(0);
    }

    // all waves done READING kb -> safe to overwrite with tile t+2
    __builtin_amdgcn_s_barrier();
    if (t + 2 < 16) stage(t + 2, kb);
  }

  // ---- combine halves through LDS (exact f32 add), then normalize ----
  // virtual pair vp = sub*2 + {0:A, 1:B}; layout identical to the anchor's
  // 4-pair epilogue.
  float lA = (lsA[0] + lsA[1]) + (lsA[2] + lsA[3]);
  float lB = (lsB[0] + lsB[1]) + (lsB[2] + lsB[3]);
  float lcolA = lA + __shfl_xor(lA, 32);
  float lcolB = lB + __shfl_xor(lB, 32);
  if (half) {
    float* dstA = (float*)smem + (sub * 2 + 0) * 2112;   // stride 33: bank-free
    float* dstB = (float*)smem + (sub * 2 + 1) * 2112;
    for (int di = 0; di < 2; ++di)
      for (int r = 0; r < 16; ++r) {
        dstA[L * 33 + di * 16 + r] = oA[di][r];
        dstB[L * 33 + di * 16 + r] = oB[di][r];
      }
    if (h5 == 0) {
      ((float*)(smem + 33792))[(sub * 2 + 0) * 32 + l31] = lcolA;
      ((float*)(smem + 33792))[(sub * 2 + 1) * 32 + l31] = lcolB;
    }
  }
  __syncthreads();
  float linvA = 0.f, linvB = 0.f;
  if (!half) {
    float* srcA = (float*)smem + (sub * 2 + 0) * 2112;
    float* srcB = (float*)smem + (sub * 2 + 1) * 2112;
    for (int di = 0; di < 2; ++di)
      for (int r = 0; r < 16; ++r) {
        oA[di][r] += srcA[L * 33 + di * 16 + r];
        oB[di][r] += srcB[L * 33 + di * 16 + r];
      }
    float loA = ((float*)(smem + 33792))[(sub * 2 + 0) * 32 + l31];
    float loB = ((float*)(smem + 33792))[(sub * 2 + 1) * 32 + l31];
    linvA = 1.f / (lcolA + loA);
    linvB = 1.f / (lcolB + loB);
  }
  __syncthreads();
  if (!half) {
    // O^T/l -> per-vp LDS tile [32 q][68 d-stride] -> coalesced store
    char* otA = smem + (sub * 2 + 0) * 4352;
    char* otB = smem + (sub * 2 + 1) * 4352;
    for (int di = 0; di < 2; ++di)
      for (int g = 0; g < 4; ++g) {
        bf16x4 pkA, pkB;
        for (int r = 0; r < 4; ++r) {
          pkA[r] = (bf16)(oA[di][g * 4 + r] * linvA);
          pkB[r] = (bf16)(oB[di][g * 4 + r] * linvB);
        }
        int d0 = di * 32 + g * 8 + h5 * 4;
        *(bf16x4*)(otA + (l31 * 68 + d0) * 2) = pkA;
        *(bf16x4*)(otB + (l31 * 68 + d0) * 2) = pkB;
      }
    for (int i = 0; i < 4; ++i) {
      int qloc = (L >> 3) + i * 8;
      int cc = L & 7;
      bf16x8 vA = *(const bf16x8*)(otA + (qloc * 68 + cc * 8) * 2);
      bf16x8 vB = *(const bf16x8*)(otB + (qloc * 68 + cc * 8) * 2);
      *(bf16x8*)(Ob + (long)(b * 2048 + q0 + qloc) * 1024 + h * 64 + cc * 8) = vA;
      *(bf16x8*)(Ob + (long)(b * 2048 + q0 + 32 + qloc) * 1024 + h * 64 + cc * 8) = vB;
    }
  }
}

// ---------------------------------------------------------------------------
extern "C" void kernel_launch(void* const* d_in, const int* in_sizes, int n_in,
                              void* d_out, int out_size, void* d_ws, size_t ws_size,
                              hipStream_t stream) {
  const float* x   = (const float*)d_in[0];
  const float* Wq  = (const float*)d_in[1];
  const float* bq  = (const float*)d_in[2];
  const float* Wk  = (const float*)d_in[3];
  const float* bk  = (const float*)d_in[4];
  const float* Wv  = (const float*)d_in[5];
  const float* bv  = (const float*)d_in[6];
  const float* Wp  = (const float*)d_in[7];
  const float* bp  = (const float*)d_in[8];
  const float* lq1 = (const float*)d_in[9];
  const float* lk1 = (const float*)d_in[10];
  const float* lq2 = (const float*)d_in[11];
  const float* lk2 = (const float*)d_in[12];
  float* out = (float*)d_out;

  // ws layout: pad | xb(8MB) | Wqkv(6MB) | Wpb(2MB) | Vt(8MB) | Ob(8MB)
  char* ws = (char*)d_ws;
  bf16* xb   = (bf16*)(ws + 1024);
  bf16* Wqkv = xb + (long)4096 * 1024;
  bf16* Wpb  = Wqkv + (long)3 * 1024 * 1024;
  bf16* Vt   = Wpb + (long)1024 * 1024;       // [32 bh][64 d][2048 slot]
  bf16* Ob   = Vt + (long)4096 * 1024;
  // Q/K bf16 tensors live in d_out (16MB); dead before final GEMM writes it
  bf16* Qb = (bf16*)d_out;
  bf16* Kb = Qb + (long)4096 * 1024;

  cast5_kernel<<<dim3(4096), 256, 0, stream>>>(
      x, Wq, Wk, Wv, Wp, lq1, lk1, lq2, lk2, xb, Wqkv, Wpb);
  gemm_qkv_kernel<<<dim3(32, 24), 256, 0, stream>>>(
      xb, Wqkv, bq, bk, bv, Qb, Kb, Vt);
  attn_kernel<<<dim3(32, 16), 256, 0, stream>>>(Qb, Kb, Vt, Ob);
  gemm_proj_kernel<<<dim3(32, 8), 256, 0, stream>>>(Ob, Wpb, bp, out);
}

// Round 14
// 202.925 us; speedup vs baseline: 1.0340x; 1.0075x over previous
//
#include <hip/hip_runtime.h>

typedef __bf16 bf16;
typedef __bf16 bf16x8 __attribute__((ext_vector_type(8)));
typedef __bf16 bf16x4 __attribute__((ext_vector_type(4)));
typedef float  f32x16 __attribute__((ext_vector_type(16)));
typedef unsigned int uint;
typedef unsigned int uintx4 __attribute__((ext_vector_type(4)));

#define QSCALE (0.125f * 1.44269504088896340736f)   // 1/sqrt(64) * log2(e), folded into Q

__device__ __forceinline__ void g2l16(const void* g, void* l) {
  __builtin_amdgcn_global_load_lds(
      (const __attribute__((address_space(1))) void*)g,
      (__attribute__((address_space(3))) void*)l, 16, 0, 0);
}

__device__ __forceinline__ f32x16 mfma16(bf16x8 a, bf16x8 b, f32x16 c) {
  return __builtin_amdgcn_mfma_f32_32x32x16_bf16(a, b, c, 0, 0, 0);
}

// ---------------------------------------------------------------------------
// Session invariants (measured over 14 rounds):
//  - attn (8-wave v5 form) is at a latency floor: time invariant under
//    halved LDS traffic/conflicts (v13), halved waves (v13), doubled ILP,
//    staging depth, occupancy repartition. Per-SIMD MFMA issue (512 cyc/iter)
//    and trans issue (512 cyc/iter) are the invariants time tracks.
//  - attn v5 body sits at the 128-VGPR cap; widened live ranges spill.
//    Spill tripwire = FETCH/WRITE balloon (VGPR_Count lies).
//  - LDS slot map must keep lane pairs contiguous in global (g2l16
//    coalescing); 2-way read bank-alias costs +4cyc/b128 but is NOT on the
//    critical path (v13: conflicts halved, time flat).
//  - v14 lever: gemm_qkv 768 blocks @2/CU = 1.5 dispatch rounds (256-block
//    tail at half machine). launch_bounds(256,3) -> 3 blocks/CU -> 1 round.
// ---------------------------------------------------------------------------

// ---------------------------------------------------------------------------
// f32 -> bf16 casts. seg0: x; seg1..3: Wq/Wk/Wv -> Wqkv; seg4: Wp -> Wpb with
// the differential-combine folded into the weight:
//   Wpb[n,k]      = Wp[n,k]                      (k < 512)
//   Wpb[n,512+j]  = Wp[n,512+j] - lv*Wp[n,j]     (j < 512)
// lv recomputed inline per seg-4 wave (tiny reduction; saves a kernel).
// ---------------------------------------------------------------------------
__global__ void cast5_kernel(const float* __restrict__ x,
                             const float* __restrict__ wq, const float* __restrict__ wk,
                             const float* __restrict__ wv, const float* __restrict__ wp,
                             const float* __restrict__ lq1, const float* __restrict__ lk1,
                             const float* __restrict__ lq2, const float* __restrict__ lk2,
                             bf16* __restrict__ xb, bf16* __restrict__ wqkv,
                             bf16* __restrict__ wpb) {
  int bx = blockIdx.x;
  int seg, idx;
  if (bx < 2048) { seg = 0; idx = bx; }
  else { int t = bx - 2048; seg = 1 + (t >> 9); idx = t & 511; }
  long i = (long)(idx * 256 + threadIdx.x) * 8;
  const float* s; bf16* d;
  if (seg == 0)      { s = x;  d = xb; }
  else if (seg == 1) { s = wq; d = wqkv; }
  else if (seg == 2) { s = wk; d = wqkv + 1048576; }
  else if (seg == 3) { s = wv; d = wqkv + 2097152; }
  else               { s = wp; d = wpb; }
  float4 f0 = *(const float4*)(s + i);
  float4 f1 = *(const float4*)(s + i + 4);
  if (seg == 4 && (i & 1023) >= 512) {
    int t = threadIdx.x & 63;
    float accum = 0.f;
    for (int hh = 0; hh < 8; ++hh) {
      float v1 = lq1[hh*64 + t] * lk1[hh*64 + t];
      float v2 = lq2[hh*64 + t] * lk2[hh*64 + t];
      for (int off = 32; off; off >>= 1) {
        v1 += __shfl_xor(v1, off);
        v2 += __shfl_xor(v2, off);
      }
      accum += expf(fminf(v1, 5.f)) - expf(fminf(v2, 5.f));
    }
    float lv = accum / 8.f + 0.8f;
    float4 g0 = *(const float4*)(s + i - 512);
    float4 g1 = *(const float4*)(s + i - 508);
    f0.x -= lv * g0.x; f0.y -= lv * g0.y; f0.z -= lv * g0.z; f0.w -= lv * g0.w;
    f1.x -= lv * g1.x; f1.y -= lv * g1.y; f1.z -= lv * g1.z; f1.w -= lv * g1.w;
  }
  bf16x8 o;
  o[0] = (bf16)f0.x; o[1] = (bf16)f0.y; o[2] = (bf16)f0.z; o[3] = (bf16)f0.w;
  o[4] = (bf16)f1.x; o[5] = (bf16)f1.y; o[6] = (bf16)f1.z; o[7] = (bf16)f1.w;
  *(bf16x8*)(d + i) = o;
}

// ---------------------------------------------------------------------------
// QKV fused NT GEMM: 128x128 tile, BK=64. grid (32, 24); by = nblk>>3 picks
// Q/K/V. Q scaled by QSCALE. V written transposed AND key-permuted into
// Vt[bh][d][slot]: within each 64-token tile, token tau = 8*Qp + 4*h5 + r
// goes to slot = 16*(Qp>>1) + 8*h5 + 4*(Qp&1) + r.  This permutation makes
// the attention PV B-fragment equal each lane's own 8 consecutive S-regs
// (no cross-lane shuffles) while A-fragment reads stay unchanged.
// V epilogue goes through a padded LDS tile so global stores are
// row-contiguous (256B/instr coalesced) instead of 8B x 32-line scatter.
// v14: launch_bounds(256,3) -> 3 blocks/CU (LDS 102KB<=160, VGPR cap ~170):
// all 768 blocks resident in ONE dispatch round (was 1.5 rounds @ 2/CU).
// ---------------------------------------------------------------------------
__global__ __launch_bounds__(256, 3) void gemm_qkv_kernel(
    const bf16* __restrict__ A, const bf16* __restrict__ B,
    const float* __restrict__ bias0, const float* __restrict__ bias1,
    const float* __restrict__ bias2,
    bf16* __restrict__ O0, bf16* __restrict__ O1, bf16* __restrict__ O2) {
  __shared__ __align__(16) char smem[34 * 1024];   // K-loop uses 32KB; V-epi 33KB
  const int tid = threadIdx.x;
  const int w = tid >> 6, L = tid & 63;
  const int l31 = L & 31, h5 = L >> 5;
  const int m0 = blockIdx.x * 128;
  const int n0g = blockIdx.y * 128;
  const int by = n0g >> 10;
  const bf16* Bp = B + (long)by * 1048576;
  const float* biasp = (by == 0) ? bias0 : ((by == 1) ? bias1 : bias2);
  const int nloc = n0g & 1023;

  f32x16 acc[2][2];
  for (int i = 0; i < 2; ++i) for (int j = 0; j < 2; ++j)
    for (int r = 0; r < 16; ++r) acc[i][j][r] = 0.f;

  const int srow = L >> 1, spar = L & 1;
  const int wm = w >> 1, wn = w & 1;
  const int fs = (l31 * 2 + h5) * 16;

  for (int k0 = 0; k0 < 1024; k0 += 64) {
    for (int i = 0; i < 8; ++i) {
      int r = w * 8 + i;
      int rr = r & 15;
      int rowblk = rr >> 2, kst = rr & 3;
      int row = rowblk * 32 + srow;
      int kk = k0 + (kst * 2 + spar) * 8;
      const bf16* gsrc = (r < 16) ? (A + (long)(m0 + row) * 1024 + kk)
                                  : (Bp + (long)(nloc + row) * 1024 + kk);
      g2l16(gsrc, smem + r * 1024);
    }
    __syncthreads();
    for (int kst = 0; kst < 4; ++kst) {
      bf16x8 a0 = *(const bf16x8*)(smem + (((wm * 2 + 0) * 4 + kst) * 1024) + fs);
      bf16x8 a1 = *(const bf16x8*)(smem + (((wm * 2 + 1) * 4 + kst) * 1024) + fs);
      bf16x8 b0 = *(const bf16x8*)(smem + 16384 + (((wn * 2 + 0) * 4 + kst) * 1024) + fs);
      bf16x8 b1 = *(const bf16x8*)(smem + 16384 + (((wn * 2 + 1) * 4 + kst) * 1024) + fs);
      acc[0][0] = mfma16(a0, b0, acc[0][0]);
      acc[0][1] = mfma16(a0, b1, acc[0][1]);
      acc[1][0] = mfma16(a1, b0, acc[1][0]);
      acc[1][1] = mfma16(a1, b1, acc[1][1]);
    }
    __syncthreads();
  }

  if (by == 2) {
    // ---- V epilogue via LDS bounce ----
    bf16* vt = (bf16*)smem;
    int b = m0 >> 11;
    int nbase = (m0 & 2047);
    for (int mi = 0; mi < 2; ++mi) for (int ni = 0; ni < 2; ++ni) {
      int lcol = wn * 64 + ni * 32 + l31;
      float bias_v = biasp[nloc + lcol];
      for (int g = 0; g < 4; ++g) {
        bf16x4 pk;
        for (int r = 0; r < 4; ++r) pk[r] = (bf16)(acc[mi][ni][g * 4 + r] + bias_v);
        int Qp = mi * 4 + g;
        int lslot = wm * 64 + (Qp >> 1) * 16 + h5 * 8 + (Qp & 1) * 4;
        *(bf16x4*)(vt + lcol * 132 + lslot) = pk;
      }
    }
    __syncthreads();
    for (int rr = 0; rr < 32; ++rr) {
      int lcol = w * 32 + rr;
      int col = nloc + lcol;
      int hh = col >> 6, d = col & 63;
      uint val = *(const uint*)(vt + lcol * 132 + L * 2);
      *(uint*)(O2 + ((long)(b * 16 + hh) * 64 + d) * 2048 + nbase + L * 2) = val;
    }
  } else {
    bf16* dst = (by == 0) ? O0 : O1;
    float scale = (by == 0) ? QSCALE : 1.0f;
    for (int mi = 0; mi < 2; ++mi) for (int ni = 0; ni < 2; ++ni) {
      int col = nloc + wn * 64 + ni * 32 + l31;
      float bias_v = biasp[col];
      int row_base = m0 + wm * 64 + mi * 32 + 4 * h5;
      for (int reg = 0; reg < 16; ++reg) {
        int rowoff = (reg & 3) + 8 * (reg >> 2);
        float v = (acc[mi][ni][reg] + bias_v) * scale;
        dst[(long)(row_base + rowoff) * 1024 + col] = (bf16)v;
      }
    }
  }
}

// ---------------------------------------------------------------------------
// Projection GEMM: 128x128 tile, clone of the proven gemm_qkv loop, f32 out
// + bias. grid (32,8) = 256 blocks (1/CU, single clean round).
// ---------------------------------------------------------------------------
__global__ __launch_bounds__(256, 2) void gemm_proj_kernel(
    const bf16* __restrict__ A, const bf16* __restrict__ B,
    const float* __restrict__ bias, float* __restrict__ Of) {
  __shared__ __align__(16) char smem[32 * 1024];
  const int tid = threadIdx.x;
  const int w = tid >> 6, L = tid & 63;
  const int l31 = L & 31, h5 = L >> 5;
  const int m0 = blockIdx.x * 128;
  const int n0 = blockIdx.y * 128;

  f32x16 acc[2][2];
  for (int i = 0; i < 2; ++i) for (int j = 0; j < 2; ++j)
    for (int r = 0; r < 16; ++r) acc[i][j][r] = 0.f;

  const int srow = L >> 1, spar = L & 1;
  const int wm = w >> 1, wn = w & 1;
  const int fs = (l31 * 2 + h5) * 16;

  for (int k0 = 0; k0 < 1024; k0 += 64) {
    for (int i = 0; i < 8; ++i) {
      int r = w * 8 + i;
      int rr = r & 15;
      int rowblk = rr >> 2, kst = rr & 3;
      int row = rowblk * 32 + srow;
      int kk = k0 + (kst * 2 + spar) * 8;
      const bf16* gsrc = (r < 16) ? (A + (long)(m0 + row) * 1024 + kk)
                                  : (B + (long)(n0 + row) * 1024 + kk);
      g2l16(gsrc, smem + r * 1024);
    }
    __syncthreads();
    for (int kst = 0; kst < 4; ++kst) {
      bf16x8 a0 = *(const bf16x8*)(smem + (((wm * 2 + 0) * 4 + kst) * 1024) + fs);
      bf16x8 a1 = *(const bf16x8*)(smem + (((wm * 2 + 1) * 4 + kst) * 1024) + fs);
      bf16x8 b0 = *(const bf16x8*)(smem + 16384 + (((wn * 2 + 0) * 4 + kst) * 1024) + fs);
      bf16x8 b1 = *(const bf16x8*)(smem + 16384 + (((wn * 2 + 1) * 4 + kst) * 1024) + fs);
      acc[0][0] = mfma16(a0, b0, acc[0][0]);
      acc[0][1] = mfma16(a0, b1, acc[0][1]);
      acc[1][0] = mfma16(a1, b0, acc[1][0]);
      acc[1][1] = mfma16(a1, b1, acc[1][1]);
    }
    __syncthreads();
  }

  for (int mi = 0; mi < 2; ++mi) for (int ni = 0; ni < 2; ++ni) {
    int col = n0 + wn * 64 + ni * 32 + l31;
    float bias_v = bias[col];
    int row_base = m0 + wm * 64 + mi * 32 + 4 * h5;
    for (int reg = 0; reg < 16; ++reg) {
      int rowoff = (reg & 3) + 8 * (reg >> 2);
      Of[(long)(row_base + rowoff) * 1024 + col] = acc[mi][ni][reg] + bias_v;
    }
  }
}

// ---------------------------------------------------------------------------
// Flash attention, intra-block K-split (64-key tiles, 16 iters). grid
// (32 bh, 16 qt), 512 thr = 8 waves: waves 0-3 keys 0..1023, waves 4-7 keys
// 1024..2047; wave pair (w, w+4) shares a 32-query range. Fixed-reference
// softmax (p = exp2(s)); halves combined through LDS (f32) at the end.
// Vt is key-permuted (see gemm_qkv_kernel), so the PV B-fragment is each
// lane's own 8 consecutive S-regs: zero cross-lane ops in the K-loop.
//
// ANCHOR (v5): 47.7-50.0us across machines, no spill. At its latency floor:
// v13 (halved LDS traffic+conflicts, doubled ILP, 256-VGPR budget) = equal
// time. All other variants rejected with counter evidence.
// ---------------------------------------------------------------------------
__global__ __launch_bounds__(512, 4) void attn_kernel(
    const bf16* __restrict__ Qb, const bf16* __restrict__ Kb,
    const bf16* __restrict__ Vt, bf16* __restrict__ Ob) {
  // staging: buf{0,1} x [half][K 8KB | V 8KB] = 64KB.  epilogue (reuses the
  // same bytes after the loop): O-exchange 4 pairs x 8448B = 33792,
  // l at 33792..34304, transpose 4x4352.
  __shared__ __align__(16) char smem[65536];
  const int tid = threadIdx.x, w = tid >> 6, L = tid & 63;
  const int half = w >> 2, pair = w & 3;
  const int bh = blockIdx.x, qt = blockIdx.y;
  const int b = bh >> 4, h = bh & 15;
  const int q0 = qt * 128 + pair * 32;
  const int l31 = L & 31, h5 = L >> 5;
  const int srow = L >> 1, spar = L & 1;
  const int fs = (l31 * 2 + h5) * 16;

  // Q fragments (B-operand of S^T mfma), resident for the whole K loop
  bf16x8 qf[4];
  for (int kst = 0; kst < 4; ++kst)
    qf[kst] = *(const bf16x8*)(Qb + (long)(b * 2048 + q0 + l31) * 1024 + h * 64
                               + kst * 16 + h5 * 8);

  f32x16 o[2];  // [di] : O^T rows d, cols q (unnormalized partial)
  for (int i = 0; i < 2; ++i)
    for (int r = 0; r < 16; ++r) o[i][r] = 0.f;
  float ls[4] = {0.f, 0.f, 0.f, 0.f};  // 4-way partial l

  const bf16* Kbh = Kb + (long)b * 2048 * 1024 + h * 64 + (long)half * 1024 * 1024;
  const bf16* Vth = Vt + (long)bh * 64 * 2048 + half * 1024;

  char* kb0 = smem + half * 16384;            // buffer 0 (this half)
  char* kb1 = smem + 32768 + half * 16384;    // buffer 1 (this half)

  // stage tile t into buffer kb: 4 global_load_lds per wave, 16 regions/half
  auto stage = [&](int t, char* kb) {
    int n0 = t * 64;
    for (int i = 0; i < 4; ++i) {
      int r = pair * 4 + i;
      if (r < 8) {
        int nkb = r >> 2, kst = r & 3;
        const bf16* g = Kbh + (long)(n0 + nkb * 32 + srow) * 1024 + (kst * 2 + spar) * 8;
        g2l16(g, kb + r * 1024);
      } else {
        int rr = r - 8, db = rr >> 2, kst = rr & 3;
        const bf16* g = Vth + (long)(db * 32 + srow) * 2048 + n0 + (kst * 2 + spar) * 8;
        g2l16(g, kb + 8192 + rr * 1024);
      }
    }
  };

  stage(0, kb0);   // 4 loads in flight
  stage(1, kb1);   // 8 loads in flight

  for (int t = 0; t < 16; ++t) {
    char* kb = (t & 1) ? kb1 : kb0;
    // wait for THIS tile's stage (the 4 oldest); leave next tile's in flight
    if (t < 15) asm volatile("s_waitcnt vmcnt(4)" ::: "memory");
    else        asm volatile("s_waitcnt vmcnt(0)" ::: "memory");
    __builtin_amdgcn_s_barrier();

    // S^T[key][q]; zero-C folded into kst=0
    f32x16 s[2];
    {
      bf16x8 k0f = *(const bf16x8*)(kb + fs);
      bf16x8 k1f = *(const bf16x8*)(kb + 4 * 1024 + fs);
      f32x16 z = {};
      __builtin_amdgcn_s_setprio(1);
      s[0] = mfma16(k0f, qf[0], z);
      s[1] = mfma16(k1f, qf[0], z);
      __builtin_amdgcn_s_setprio(0);
    }
    for (int kst = 1; kst < 4; ++kst) {
      bf16x8 k0f = *(const bf16x8*)(kb + (kst * 1024) + fs);
      bf16x8 k1f = *(const bf16x8*)(kb + ((4 + kst) * 1024) + fs);
      __builtin_amdgcn_s_setprio(1);
      s[0] = mfma16(k0f, qf[kst], s[0]);
      s[1] = mfma16(k1f, qf[kst], s[1]);
      __builtin_amdgcn_s_setprio(0);
    }

    // p = exp2(s); accumulate l into 4 partials
    for (int nki = 0; nki < 2; ++nki)
      for (int r = 0; r < 16; ++r) {
        float p = __builtin_amdgcn_exp2f(s[nki][r]);
        s[nki][r] = p;
        ls[r & 3] += p;
      }

    // O^T += Vt_tile · P^T.  Vt global layout is key-permuted so that the
    // B-fragment for kst is exactly s[kst>>1][8*(kst&1) + 0..7] in order.
    for (int kst = 0; kst < 4; ++kst) {
      bf16x8 v0 = *(const bf16x8*)(kb + 8192 + (kst * 1024) + fs);
      bf16x8 v1 = *(const bf16x8*)(kb + 8192 + ((4 + kst) * 1024) + fs);
      int nki = kst >> 1;
      int rbase = (kst & 1) * 8;
      bf16x8 pf;   // direct casts -> v_cvt_pk_bf16_f32 pairs (m240)
#pragma unroll
      for (int j = 0; j < 8; ++j) pf[j] = (bf16)s[nki][rbase + j];
      __builtin_amdgcn_s_setprio(1);
      o[0] = mfma16(v0, pf, o[0]);
      o[1] = mfma16(v1, pf, o[1]);
      __builtin_amdgcn_s_setprio(0);
    }

    // all waves done READING kb -> safe to overwrite with tile t+2
    __builtin_amdgcn_s_barrier();
    if (t + 2 < 16) stage(t + 2, kb);
  }

  // ---- combine halves through LDS (exact f32 add), then normalize ----
  float lsum = (ls[0] + ls[1]) + (ls[2] + ls[3]);
  float lcol = lsum + __shfl_xor(lsum, 32);  // per-col l of this half
  if (half) {
    float* dstO = (float*)smem + pair * 2112;   // stride 33 dwords: bank-free
    for (int di = 0; di < 2; ++di)
      for (int r = 0; r < 16; ++r) dstO[L * 33 + di * 16 + r] = o[di][r];
    if (h5 == 0) ((float*)(smem + 33792))[pair * 32 + l31] = lcol;
  }
  __syncthreads();
  float linv = 0.f;
  if (!half) {
    float* srcO = (float*)smem + pair * 2112;
    for (int di = 0; di < 2; ++di)
      for (int r = 0; r < 16; ++r) o[di][r] += srcO[L * 33 + di * 16 + r];
    float lother = ((float*)(smem + 33792))[pair * 32 + l31];
    linv = 1.f / (lcol + lother);
  }
  __syncthreads();
  if (!half) {
    // O^T/l -> per-wave LDS tile [32 q][68 d-stride] -> coalesced store
    char* ot = smem + pair * 4352;
    for (int di = 0; di < 2; ++di)
      for (int g = 0; g < 4; ++g) {
        bf16x4 pk;
        for (int r = 0; r < 4; ++r)
          pk[r] = (bf16)(o[di][g * 4 + r] * linv);
        int d0 = di * 32 + g * 8 + h5 * 4;
        *(bf16x4*)(ot + (l31 * 68 + d0) * 2) = pk;
      }
    for (int i = 0; i < 4; ++i) {
      int qloc = (L >> 3) + i * 8;
      int cc = L & 7;
      bf16x8 vv = *(const bf16x8*)(ot + (qloc * 68 + cc * 8) * 2);
      *(bf16x8*)(Ob + (long)(b * 2048 + q0 + qloc) * 1024 + h * 64 + cc * 8) = vv;
    }
  }
}

// ---------------------------------------------------------------------------
extern "C" void kernel_launch(void* const* d_in, const int* in_sizes, int n_in,
                              void* d_out, int out_size, void* d_ws, size_t ws_size,
                              hipStream_t stream) {
  const float* x   = (const float*)d_in[0];
  const float* Wq  = (const float*)d_in[1];
  const float* bq  = (const float*)d_in[2];
  const float* Wk  = (const float*)d_in[3];
  const float* bk  = (const float*)d_in[4];
  const float* Wv  = (const float*)d_in[5];
  const float* bv  = (const float*)d_in[6];
  const float* Wp  = (const float*)d_in[7];
  const float* bp  = (const float*)d_in[8];
  const float* lq1 = (const float*)d_in[9];
  const float* lk1 = (const float*)d_in[10];
  const float* lq2 = (const float*)d_in[11];
  const float* lk2 = (const float*)d_in[12];
  float* out = (float*)d_out;

  // ws layout: pad | xb(8MB) | Wqkv(6MB) | Wpb(2MB) | Vt(8MB) | Ob(8MB)
  char* ws = (char*)d_ws;
  bf16* xb   = (bf16*)(ws + 1024);
  bf16* Wqkv = xb + (long)4096 * 1024;
  bf16* Wpb  = Wqkv + (long)3 * 1024 * 1024;
  bf16* Vt   = Wpb + (long)1024 * 1024;       // [32 bh][64 d][2048 slot]
  bf16* Ob   = Vt + (long)4096 * 1024;
  // Q/K bf16 tensors live in d_out (16MB); dead before final GEMM writes it
  bf16* Qb = (bf16*)d_out;
  bf16* Kb = Qb + (long)4096 * 1024;

  cast5_kernel<<<dim3(4096), 256, 0, stream>>>(
      x, Wq, Wk, Wv, Wp, lq1, lk1, lq2, lk2, xb, Wqkv, Wpb);
  gemm_qkv_kernel<<<dim3(32, 24), 256, 0, stream>>>(
      xb, Wqkv, bq, bk, bv, Qb, Kb, Vt);
  attn_kernel<<<dim3(32, 16), 512, 0, stream>>>(Qb, Kb, Vt, Ob);
  gemm_proj_kernel<<<dim3(32, 8), 256, 0, stream>>>(Ob, Wpb, bp, out);
}